// Round 7
// baseline (1393243.164 us; speedup 1.0000x reference)
//
#include <hip/hip_runtime.h>

// LSTM_61203283968689 — R13: barrier-free dataflow pipeline via LDS flags.
// KEY COUNTER INSIGHT (R6..R12): VALUBusy ~= MfmaUtil every round (within 1-4%)
// -> the gfx94x-fallback VALUBusy formula counts MFMA execution; true VALU is
// only ~260cy/SIMD/tick. Budget: tick 1600 = 746 MFMA + ~260 VALU + ~600 STALL.
// The per-tick __syncthreads re-locks the 3 waves/SIMD into lockstep: their
// MFMAs interleave in the shared matrix-pipe FIFO, ALL complete near the end of
// the ~750cy drain, then all ew trans chains (~200cy latency) run with the
// matrix pipe idle, then all hit write/barrier together. Source order (R9/R10)
// and setprio (R12) cannot change a FIFO completion profile -> all null.
// R13 removes the barrier: per-wave LDS flags, diagonal lag 1 tick/layer,
// h ring depth 4. Wave (layer l, tick T, step s=T-l) waits:
//   own-group min4 >= T-1   (self h(s-1) complete)
//   upstream min4 >= T-1    (h_{l-1}(s) complete)          [l>0]
//   downstream min4 >= T-3  (readers of h_l(s-4) done)     [l<2]
// All targets reference strictly earlier ticks -> acyclic -> deadlock-free;
// ring-slot collision checked for max drift (+1 own, +3 cross). Layer groups
// drift into anti-phase (L0 lighter: 12 vs 16 MFMA) so one group's MFMA burst
// fills another's ew/stall window. Fast path: 3 non-volatile b128 flag loads;
// slow path: volatile spin + s_sleep + bounded guard (bug -> FAIL not hang).
// Math identical to R7 (bias, ih-lo, ih-hi, hh-lo, hh-hi per gate) -> absmax
// unchanged. LDS: XL 64K + rings 24K + flags = 88.1 KiB -> 1 block/CU.

#define TT   512
#define NTH  768
#define NBLK 256

typedef _Float16 h16;
typedef __attribute__((ext_vector_type(8))) _Float16 h16x8;
typedef __attribute__((ext_vector_type(4))) float f32x4;

#define MFMA16(a, b, c) __builtin_amdgcn_mfma_f32_16x16x32_f16((a), (b), (c), 0, 0, 0)

__device__ __forceinline__ float sigm(float z) {
    return __builtin_amdgcn_rcpf(1.f + __expf(-z));
}

// B-fragment: 8 consecutive k of row `ro` from row-major W[.,ld], f32 -> f16.
__device__ __forceinline__ h16x8 loadB(const float* __restrict__ W, int ld, int ro,
                                       int k0, int kmax) {
    h16x8 r;
    #pragma unroll
    for (int i = 0; i < 8; ++i) {
        const int k = k0 + i;
        r[i] = (h16)((k < kmax) ? W[(size_t)ro * ld + k] : 0.f);
    }
    return r;
}

__global__ __attribute__((amdgpu_flat_work_group_size(NTH, NTH), amdgpu_waves_per_eu(3)))
void lstm_mfma(
    const float* __restrict__ x,
    const float* __restrict__ wih0, const float* __restrict__ whh0,
    const float* __restrict__ bih0, const float* __restrict__ bhh0,
    const float* __restrict__ wih1, const float* __restrict__ whh1,
    const float* __restrict__ bih1, const float* __restrict__ bhh1,
    const float* __restrict__ wih2, const float* __restrict__ whh2,
    const float* __restrict__ bih2, const float* __restrict__ bhh2,
    const float* __restrict__ wfc, const float* __restrict__ bfc,
    float* __restrict__ out)
{
    const int tid  = threadIdx.x;
    const int w    = tid >> 6;        // wave 0..11 (= 4*wl + wg)
    const int wl   = w >> 2;          // layer 0..2
    const int wg   = w & 3;           // gate-tile group: units [16wg, 16wg+16)
    const int lane = tid & 63;
    const int nloc = lane & 15;
    const int kg   = lane >> 4;       // k-group 0..3 ; also sample (C-row 4*kg)
    const int b4   = blockIdx.x * 4;
    const int u    = wg * 16 + nloc;

    // LDS: XL 64 KiB + HR 24 KiB + FL = 88.1 KiB -> 1 block/CU
    __shared__ alignas(16) h16 XL[2 * 32 * 512];   // x, 2 chunks x 32 t x frag-tile(512)
    __shared__ alignas(16) h16 HR[3 * 4 * 1024];   // h ring: layer*4096 + (s&3)*1024
    __shared__ alignas(16) int FL[16];             // per-wave tick flags [0..11]

    // ---------------- B fragments for THIS wave's layer only ----------------
    h16x8 Bf[4][4];
    float bias[4];
    #pragma unroll
    for (int g = 0; g < 4; ++g) {
        const int ro = g * 64 + u;
        if (wl == 0) {
            Bf[g][0] = loadB(wih0, 22, ro, kg * 8,      22);
            Bf[g][1] = loadB(whh0, 64, ro, kg * 8,      64);
            Bf[g][2] = loadB(whh0, 64, ro, 32 + kg * 8, 64);
            Bf[g][3] = Bf[g][2];
            bias[g]  = bih0[ro] + bhh0[ro];
        } else if (wl == 1) {
            Bf[g][0] = loadB(wih1, 64, ro, kg * 8,      64);
            Bf[g][1] = loadB(wih1, 64, ro, 32 + kg * 8, 64);
            Bf[g][2] = loadB(whh1, 64, ro, kg * 8,      64);
            Bf[g][3] = loadB(whh1, 64, ro, 32 + kg * 8, 64);
            bias[g]  = bih1[ro] + bhh1[ro];
        } else {
            Bf[g][0] = loadB(wih2, 64, ro, kg * 8,      64);
            Bf[g][1] = loadB(wih2, 64, ro, 32 + kg * 8, 64);
            Bf[g][2] = loadB(whh2, 64, ro, kg * 8,      64);
            Bf[g][3] = loadB(whh2, 64, ro, 32 + kg * 8, 64);
            bias[g]  = bih2[ro] + bhh2[ro];
        }
    }

    // ---------------- zero LDS (pad rows must stay zero), init flags ----------------
    {
        int* xz = (int*)XL;
        for (int i = tid; i < 2 * 32 * 256; i += NTH) xz[i] = 0;
        int* hz = (int*)HR;
        for (int i = tid; i < 3 * 4 * 512; i += NTH) hz[i] = 0;
        if (tid < 16) FL[tid] = -1;
    }
    __syncthreads();

    // ---------------- x staging: sample bl -> A-row 4*bl, frag layout ------------
    auto stage_x = [&](int chunk) {
        if (tid < 4 * 22) {
            const int bl = tid / 22, ii = tid - bl * 22;
            const float* src = x + (size_t)(b4 + bl) * (22 * 512) + (size_t)ii * 512
                                 + chunk * 32;
            h16* dst = &XL[(chunk & 1) * (32 * 512) + (ii >> 3) * 128 + (4 * bl) * 8 + (ii & 7)];
            #pragma unroll
            for (int q = 0; q < 8; ++q) {
                const float4 v = ((const float4*)src)[q];
                dst[(q * 4 + 0) * 512] = (h16)v.x;
                dst[(q * 4 + 1) * 512] = (h16)v.y;
                dst[(q * 4 + 2) * 512] = (h16)v.z;
                dst[(q * 4 + 3) * 512] = (h16)v.w;
            }
        }
    };
    stage_x(0);

    const int lo8  = lane * 8;
    const int hoff = (u >> 3) * 128 + kg * 32 + (u & 7);

    float cst = 0.f;

    auto ew = [&](const f32x4& zi, const f32x4& zf, const f32x4& zg, const f32x4& zo,
                  h16* hb) {
        const float vi = sigm(zi[0]);
        const float vf = sigm(zf[0]);
        const float vg = 2.f * sigm(2.f * zg[0]) - 1.f;
        const float vo = sigm(zo[0]);
        const float c  = vf * cst + vi * vg;
        cst = c;
        hb[hoff] = (h16)(vo * (2.f * sigm(2.f * c) - 1.f));
    };

    f32x4 zb[4];
    #pragma unroll
    for (int g = 0; g < 4; ++g) zb[g] = f32x4{bias[g], 0.f, 0.f, 0.f};

    __syncthreads();   // x chunk 0 + zeroed rings + flags visible; last block barrier
                       // until the epilogue — steady state is flag-synced only.

    volatile int* vFL = FL;

    // slow-path wait: volatile spin + sleep + bounded guard (bug -> FAIL, not hang)
    auto waitge = [&](int idx, int tgt) {
        if (vFL[idx] >= tgt) return;
        int guard = 0;
        while (vFL[idx] < tgt) {
            __builtin_amdgcn_s_sleep(1);
            if (++guard > (1 << 22)) return;   // safety valve
        }
    };
    // group wait with fast path: one b128 load of 4 flags, min >= tgt
    auto waitgrp = [&](int g, int tgt) {
        const int4 f = *(const int4*)&FL[4 * g];
        const int m = min(min(f.x, f.y), min(f.z, f.w));
        if (m >= tgt) return;
        waitge(4 * g + 0, tgt); waitge(4 * g + 1, tgt);
        waitge(4 * g + 2, tgt); waitge(4 * g + 3, tgt);
    };
    // own flag at wait time is exactly T-1, so min4(own group) >= T-1 works.

    auto post = [&](int T) {
        asm volatile("s_waitcnt lgkmcnt(0)" ::: "memory");  // h write landed
        if (lane == 0) vFL[w] = T;
        asm volatile("" ::: "memory");
    };

    // ============================ dataflow tick loops ============================
    if (wl == 0) {               // L0: step s = T; consumes x(s), h0(s-1)
        #pragma unroll 1
        for (int T = 0; T < TT; ++T) {
            const int s = T;
            waitgrp(0, T - 1);           // own group (self h(s-1))
            waitgrp(1, T - 3);           // downstream readers of h0(s-4)
            asm volatile("" ::: "memory");
            const h16* sr = HR + 0 * 4096 + ((s - 1) & 3) * 1024;
            h16*       sw = HR + 0 * 4096 + (s & 3) * 1024;
            const h16x8 ax  = *(const h16x8*)&XL[((s >> 5) & 1) * (32 * 512)
                                                 + (s & 31) * 512 + lo8];
            const h16x8 alo = *(const h16x8*)(sr + lo8);
            const h16x8 ahi = *(const h16x8*)(sr + lo8 + 512);
            f32x4 z[4];
            #pragma unroll
            for (int g = 0; g < 4; ++g) {
                z[g] = MFMA16(ax,  Bf[g][0], zb[g]);
                z[g] = MFMA16(alo, Bf[g][1], z[g]);
                z[g] = MFMA16(ahi, Bf[g][2], z[g]);
            }
            if ((T & 31) == 16 && (T >> 5) < 15) stage_x((T >> 5) + 1);
            ew(z[0], z[1], z[2], z[3], sw);
            post(T);
        }
    } else if (wl == 1) {        // L1: step s = T-1; consumes h0(s), h1(s-1)
        #pragma unroll 1
        for (int T = 1; T < TT + 1; ++T) {
            const int s = T - 1;
            waitgrp(1, T - 1);           // own group
            waitgrp(0, T - 1);           // upstream h0(s)
            waitgrp(2, T - 3);           // downstream readers of h1(s-4)
            asm volatile("" ::: "memory");
            const h16* ur = HR + 0 * 4096 + (s & 3) * 1024;
            const h16* sr = HR + 1 * 4096 + ((s - 1) & 3) * 1024;
            h16*       sw = HR + 1 * 4096 + (s & 3) * 1024;
            const h16x8 ulo = *(const h16x8*)(ur + lo8);
            const h16x8 uhi = *(const h16x8*)(ur + lo8 + 512);
            const h16x8 alo = *(const h16x8*)(sr + lo8);
            const h16x8 ahi = *(const h16x8*)(sr + lo8 + 512);
            f32x4 z[4];
            #pragma unroll
            for (int g = 0; g < 4; ++g) {
                z[g] = MFMA16(ulo, Bf[g][0], zb[g]);
                z[g] = MFMA16(uhi, Bf[g][1], z[g]);
                z[g] = MFMA16(alo, Bf[g][2], z[g]);
                z[g] = MFMA16(ahi, Bf[g][3], z[g]);
            }
            ew(z[0], z[1], z[2], z[3], sw);
            post(T);
        }
    } else {                     // L2: step s = T-2; consumes h1(s), h2(s-1)
        #pragma unroll 1
        for (int T = 2; T < TT + 2; ++T) {
            const int s = T - 2;
            waitgrp(2, T - 1);           // own group
            waitgrp(1, T - 1);           // upstream h1(s)
            asm volatile("" ::: "memory");
            const h16* ur = HR + 1 * 4096 + (s & 3) * 1024;
            const h16* sr = HR + 2 * 4096 + ((s - 1) & 3) * 1024;
            h16*       sw = HR + 2 * 4096 + (s & 3) * 1024;
            const h16x8 ulo = *(const h16x8*)(ur + lo8);
            const h16x8 uhi = *(const h16x8*)(ur + lo8 + 512);
            const h16x8 alo = *(const h16x8*)(sr + lo8);
            const h16x8 ahi = *(const h16x8*)(sr + lo8 + 512);
            f32x4 z[4];
            #pragma unroll
            for (int g = 0; g < 4; ++g) {
                z[g] = MFMA16(ulo, Bf[g][0], zb[g]);
                z[g] = MFMA16(uhi, Bf[g][1], z[g]);
                z[g] = MFMA16(alo, Bf[g][2], z[g]);
                z[g] = MFMA16(ahi, Bf[g][3], z[g]);
            }
            ew(z[0], z[1], z[2], z[3], sw);
            post(T);
        }
    }

    __syncthreads();   // join all waves before the epilogue

    // ------------- FC epilogue: h2(step 511) in ring slot 511&3 = 3 -----------
    if (tid < 16) {
        const int ms = tid >> 2, o = tid & 3;
        const h16* h2 = HR + 2 * 4096 + 3 * 1024;
        float acc = bfc[o];
        #pragma unroll 1
        for (int uu = 0; uu < 64; ++uu)
            acc += (float)h2[(uu >> 3) * 128 + (4 * ms) * 8 + (uu & 7)] * wfc[o * 64 + uu];
        out[(b4 + ms) * 4 + o] = acc;
    }
}

extern "C" void kernel_launch(void* const* d_in, const int* in_sizes, int n_in,
                              void* d_out, int out_size, void* d_ws, size_t ws_size,
                              hipStream_t stream) {
    const float* x    = (const float*)d_in[0];
    const float* wih0 = (const float*)d_in[1];
    const float* whh0 = (const float*)d_in[2];
    const float* bih0 = (const float*)d_in[3];
    const float* bhh0 = (const float*)d_in[4];
    const float* wih1 = (const float*)d_in[5];
    const float* whh1 = (const float*)d_in[6];
    const float* bih1 = (const float*)d_in[7];
    const float* bhh1 = (const float*)d_in[8];
    const float* wih2 = (const float*)d_in[9];
    const float* whh2 = (const float*)d_in[10];
    const float* bih2 = (const float*)d_in[11];
    const float* bhh2 = (const float*)d_in[12];
    const float* wfc  = (const float*)d_in[13];
    const float* bfc  = (const float*)d_in[14];
    float* out = (float*)d_out;

    lstm_mfma<<<dim3(NBLK), dim3(NTH), 0, stream>>>(
        x, wih0, whh0, bih0, bhh0, wih1, whh1, bih1, bhh1,
        wih2, whh2, bih2, bhh2, wfc, bfc, out);
}

// Round 8
// 469.574 us; speedup vs baseline: 2967.0394x; 2967.0394x over previous
//
#include <hip/hip_runtime.h>

// LSTM_61203283968689 — R14: R13 dataflow pipeline + FIRST-TICK DEADLOCK FIX.
// R13 passed (absmax identical -> protocol/memory-ordering correct) but ran
// 1.39s: L1's own-group wait at its first tick T=1 targeted grp1>=0, which no
// L1 wave can post before passing that same wait -> circular deadlock among
// the 4 L1 waves, resolved only by the 2^22 guard timeout (~0.25-0.6s); same
// for L2 at T=2 (grp2>=1). Guard-released reads hit the ZEROED h(-1) ring slot
// = the correct value, hence the clean pass. Fix: own-group wait target is -1
// (trivially satisfied by init) at each group's FIRST tick, T-1 afterward.
// All other targets verified reachable (">=" satisfied by first post).
// Theory unchanged (R6..R12): VALUBusy ~= MfmaUtil every round -> the fallback
// VALUBusy counts MFMA; tick 1600cy = 746 MFMA + ~260 true VALU + ~600 STALL.
// The per-tick barrier locked the 3 waves/SIMD into lockstep (MFMAs interleave
// in the matrix-pipe FIFO, all complete together, all trans chains run with
// the pipe idle). Barrier-free + asymmetric layer load (L0=12 MFMA, L1/2=16)
// lets groups drift into anti-phase so MFMA bursts fill trans/stall windows.
// Math identical to R7 (bias, ih-lo, ih-hi, hh-lo, hh-hi per gate).
// LDS: XL 64K + HR 24K + FL = 88.1 KiB -> 1 block/CU.

#define TT   512
#define NTH  768
#define NBLK 256

typedef _Float16 h16;
typedef __attribute__((ext_vector_type(8))) _Float16 h16x8;
typedef __attribute__((ext_vector_type(4))) float f32x4;

#define MFMA16(a, b, c) __builtin_amdgcn_mfma_f32_16x16x32_f16((a), (b), (c), 0, 0, 0)

__device__ __forceinline__ float sigm(float z) {
    return __builtin_amdgcn_rcpf(1.f + __expf(-z));
}

// B-fragment: 8 consecutive k of row `ro` from row-major W[.,ld], f32 -> f16.
__device__ __forceinline__ h16x8 loadB(const float* __restrict__ W, int ld, int ro,
                                       int k0, int kmax) {
    h16x8 r;
    #pragma unroll
    for (int i = 0; i < 8; ++i) {
        const int k = k0 + i;
        r[i] = (h16)((k < kmax) ? W[(size_t)ro * ld + k] : 0.f);
    }
    return r;
}

__global__ __attribute__((amdgpu_flat_work_group_size(NTH, NTH), amdgpu_waves_per_eu(3)))
void lstm_mfma(
    const float* __restrict__ x,
    const float* __restrict__ wih0, const float* __restrict__ whh0,
    const float* __restrict__ bih0, const float* __restrict__ bhh0,
    const float* __restrict__ wih1, const float* __restrict__ whh1,
    const float* __restrict__ bih1, const float* __restrict__ bhh1,
    const float* __restrict__ wih2, const float* __restrict__ whh2,
    const float* __restrict__ bih2, const float* __restrict__ bhh2,
    const float* __restrict__ wfc, const float* __restrict__ bfc,
    float* __restrict__ out)
{
    const int tid  = threadIdx.x;
    const int w    = tid >> 6;        // wave 0..11 (= 4*wl + wg)
    const int wl   = w >> 2;          // layer 0..2
    const int wg   = w & 3;           // gate-tile group: units [16wg, 16wg+16)
    const int lane = tid & 63;
    const int nloc = lane & 15;
    const int kg   = lane >> 4;       // k-group 0..3 ; also sample (C-row 4*kg)
    const int b4   = blockIdx.x * 4;
    const int u    = wg * 16 + nloc;

    // LDS: XL 64 KiB + HR 24 KiB + FL = 88.1 KiB -> 1 block/CU
    __shared__ alignas(16) h16 XL[2 * 32 * 512];   // x, 2 chunks x 32 t x frag-tile(512)
    __shared__ alignas(16) h16 HR[3 * 4 * 1024];   // h ring: layer*4096 + (s&3)*1024
    __shared__ alignas(16) int FL[16];             // per-wave tick flags [0..11]

    // ---------------- B fragments for THIS wave's layer only ----------------
    h16x8 Bf[4][4];
    float bias[4];
    #pragma unroll
    for (int g = 0; g < 4; ++g) {
        const int ro = g * 64 + u;
        if (wl == 0) {
            Bf[g][0] = loadB(wih0, 22, ro, kg * 8,      22);
            Bf[g][1] = loadB(whh0, 64, ro, kg * 8,      64);
            Bf[g][2] = loadB(whh0, 64, ro, 32 + kg * 8, 64);
            Bf[g][3] = Bf[g][2];
            bias[g]  = bih0[ro] + bhh0[ro];
        } else if (wl == 1) {
            Bf[g][0] = loadB(wih1, 64, ro, kg * 8,      64);
            Bf[g][1] = loadB(wih1, 64, ro, 32 + kg * 8, 64);
            Bf[g][2] = loadB(whh1, 64, ro, kg * 8,      64);
            Bf[g][3] = loadB(whh1, 64, ro, 32 + kg * 8, 64);
            bias[g]  = bih1[ro] + bhh1[ro];
        } else {
            Bf[g][0] = loadB(wih2, 64, ro, kg * 8,      64);
            Bf[g][1] = loadB(wih2, 64, ro, 32 + kg * 8, 64);
            Bf[g][2] = loadB(whh2, 64, ro, kg * 8,      64);
            Bf[g][3] = loadB(whh2, 64, ro, 32 + kg * 8, 64);
            bias[g]  = bih2[ro] + bhh2[ro];
        }
    }

    // ---------------- zero LDS (pad rows must stay zero), init flags ----------------
    {
        int* xz = (int*)XL;
        for (int i = tid; i < 2 * 32 * 256; i += NTH) xz[i] = 0;
        int* hz = (int*)HR;
        for (int i = tid; i < 3 * 4 * 512; i += NTH) hz[i] = 0;
        if (tid < 16) FL[tid] = -1;
    }
    __syncthreads();

    // ---------------- x staging: sample bl -> A-row 4*bl, frag layout ------------
    auto stage_x = [&](int chunk) {
        if (tid < 4 * 22) {
            const int bl = tid / 22, ii = tid - bl * 22;
            const float* src = x + (size_t)(b4 + bl) * (22 * 512) + (size_t)ii * 512
                                 + chunk * 32;
            h16* dst = &XL[(chunk & 1) * (32 * 512) + (ii >> 3) * 128 + (4 * bl) * 8 + (ii & 7)];
            #pragma unroll
            for (int q = 0; q < 8; ++q) {
                const float4 v = ((const float4*)src)[q];
                dst[(q * 4 + 0) * 512] = (h16)v.x;
                dst[(q * 4 + 1) * 512] = (h16)v.y;
                dst[(q * 4 + 2) * 512] = (h16)v.z;
                dst[(q * 4 + 3) * 512] = (h16)v.w;
            }
        }
    };
    stage_x(0);

    const int lo8  = lane * 8;
    const int hoff = (u >> 3) * 128 + kg * 32 + (u & 7);

    float cst = 0.f;

    auto ew = [&](const f32x4& zi, const f32x4& zf, const f32x4& zg, const f32x4& zo,
                  h16* hb) {
        const float vi = sigm(zi[0]);
        const float vf = sigm(zf[0]);
        const float vg = 2.f * sigm(2.f * zg[0]) - 1.f;
        const float vo = sigm(zo[0]);
        const float c  = vf * cst + vi * vg;
        cst = c;
        hb[hoff] = (h16)(vo * (2.f * sigm(2.f * c) - 1.f));
    };

    f32x4 zb[4];
    #pragma unroll
    for (int g = 0; g < 4; ++g) zb[g] = f32x4{bias[g], 0.f, 0.f, 0.f};

    __syncthreads();   // x chunk 0 + zeroed rings + flags visible; last block barrier
                       // until the epilogue — steady state is flag-synced only.

    volatile int* vFL = FL;

    // slow-path wait: volatile spin + sleep + bounded guard (bug -> FAIL, not hang)
    auto waitge = [&](int idx, int tgt) {
        if (vFL[idx] >= tgt) return;
        int guard = 0;
        while (vFL[idx] < tgt) {
            __builtin_amdgcn_s_sleep(1);
            if (++guard > (1 << 22)) return;   // safety valve
        }
    };
    // group wait with fast path: one b128 load of 4 flags, min >= tgt
    auto waitgrp = [&](int g, int tgt) {
        const int4 f = *(const int4*)&FL[4 * g];
        const int m = min(min(f.x, f.y), min(f.z, f.w));
        if (m >= tgt) return;
        waitge(4 * g + 0, tgt); waitge(4 * g + 1, tgt);
        waitge(4 * g + 2, tgt); waitge(4 * g + 3, tgt);
    };

    auto post = [&](int T) {
        asm volatile("s_waitcnt lgkmcnt(0)" ::: "memory");  // h write landed
        if (lane == 0) vFL[w] = T;
        asm volatile("" ::: "memory");
    };

    // ============================ dataflow tick loops ============================
    if (wl == 0) {               // L0: step s = T; consumes x(s), h0(s-1)
        #pragma unroll 1
        for (int T = 0; T < TT; ++T) {
            const int s = T;
            waitgrp(0, T - 1);           // own group (first tick T=0: target -1 = init)
            waitgrp(1, T - 3);           // downstream readers of h0(s-4)
            asm volatile("" ::: "memory");
            const h16* sr = HR + 0 * 4096 + ((s - 1) & 3) * 1024;
            h16*       sw = HR + 0 * 4096 + (s & 3) * 1024;
            const h16x8 ax  = *(const h16x8*)&XL[((s >> 5) & 1) * (32 * 512)
                                                 + (s & 31) * 512 + lo8];
            const h16x8 alo = *(const h16x8*)(sr + lo8);
            const h16x8 ahi = *(const h16x8*)(sr + lo8 + 512);
            f32x4 z[4];
            #pragma unroll
            for (int g = 0; g < 4; ++g) {
                z[g] = MFMA16(ax,  Bf[g][0], zb[g]);
                z[g] = MFMA16(alo, Bf[g][1], z[g]);
                z[g] = MFMA16(ahi, Bf[g][2], z[g]);
            }
            if ((T & 31) == 16 && (T >> 5) < 15) stage_x((T >> 5) + 1);
            ew(z[0], z[1], z[2], z[3], sw);
            post(T);
        }
    } else if (wl == 1) {        // L1: step s = T-1; consumes h0(s), h1(s-1)
        #pragma unroll 1
        for (int T = 1; T < TT + 1; ++T) {
            const int s = T - 1;
            // DEADLOCK FIX: first tick (T=1) has no previous own post; target -1.
            waitgrp(1, (T == 1) ? -1 : T - 1);   // own group
            waitgrp(0, T - 1);                   // upstream h0(s)
            waitgrp(2, T - 3);                   // downstream readers of h1(s-4)
            asm volatile("" ::: "memory");
            const h16* ur = HR + 0 * 4096 + (s & 3) * 1024;
            const h16* sr = HR + 1 * 4096 + ((s - 1) & 3) * 1024;
            h16*       sw = HR + 1 * 4096 + (s & 3) * 1024;
            const h16x8 ulo = *(const h16x8*)(ur + lo8);
            const h16x8 uhi = *(const h16x8*)(ur + lo8 + 512);
            const h16x8 alo = *(const h16x8*)(sr + lo8);
            const h16x8 ahi = *(const h16x8*)(sr + lo8 + 512);
            f32x4 z[4];
            #pragma unroll
            for (int g = 0; g < 4; ++g) {
                z[g] = MFMA16(ulo, Bf[g][0], zb[g]);
                z[g] = MFMA16(uhi, Bf[g][1], z[g]);
                z[g] = MFMA16(alo, Bf[g][2], z[g]);
                z[g] = MFMA16(ahi, Bf[g][3], z[g]);
            }
            ew(z[0], z[1], z[2], z[3], sw);
            post(T);
        }
    } else {                     // L2: step s = T-2; consumes h1(s), h2(s-1)
        #pragma unroll 1
        for (int T = 2; T < TT + 2; ++T) {
            const int s = T - 2;
            // DEADLOCK FIX: first tick (T=2) has no previous own post; target -1.
            waitgrp(2, (T == 2) ? -1 : T - 1);   // own group
            waitgrp(1, T - 1);                   // upstream h1(s)
            asm volatile("" ::: "memory");
            const h16* ur = HR + 1 * 4096 + (s & 3) * 1024;
            const h16* sr = HR + 2 * 4096 + ((s - 1) & 3) * 1024;
            h16*       sw = HR + 2 * 4096 + (s & 3) * 1024;
            const h16x8 ulo = *(const h16x8*)(ur + lo8);
            const h16x8 uhi = *(const h16x8*)(ur + lo8 + 512);
            const h16x8 alo = *(const h16x8*)(sr + lo8);
            const h16x8 ahi = *(const h16x8*)(sr + lo8 + 512);
            f32x4 z[4];
            #pragma unroll
            for (int g = 0; g < 4; ++g) {
                z[g] = MFMA16(ulo, Bf[g][0], zb[g]);
                z[g] = MFMA16(uhi, Bf[g][1], z[g]);
                z[g] = MFMA16(alo, Bf[g][2], z[g]);
                z[g] = MFMA16(ahi, Bf[g][3], z[g]);
            }
            ew(z[0], z[1], z[2], z[3], sw);
            post(T);
        }
    }

    __syncthreads();   // join all waves before the epilogue

    // ------------- FC epilogue: h2(step 511) in ring slot 511&3 = 3 -----------
    if (tid < 16) {
        const int ms = tid >> 2, o = tid & 3;
        const h16* h2 = HR + 2 * 4096 + 3 * 1024;
        float acc = bfc[o];
        #pragma unroll 1
        for (int uu = 0; uu < 64; ++uu)
            acc += (float)h2[(uu >> 3) * 128 + (4 * ms) * 8 + (uu & 7)] * wfc[o * 64 + uu];
        out[(b4 + ms) * 4 + o] = acc;
    }
}

extern "C" void kernel_launch(void* const* d_in, const int* in_sizes, int n_in,
                              void* d_out, int out_size, void* d_ws, size_t ws_size,
                              hipStream_t stream) {
    const float* x    = (const float*)d_in[0];
    const float* wih0 = (const float*)d_in[1];
    const float* whh0 = (const float*)d_in[2];
    const float* bih0 = (const float*)d_in[3];
    const float* bhh0 = (const float*)d_in[4];
    const float* wih1 = (const float*)d_in[5];
    const float* whh1 = (const float*)d_in[6];
    const float* bih1 = (const float*)d_in[7];
    const float* bhh1 = (const float*)d_in[8];
    const float* wih2 = (const float*)d_in[9];
    const float* whh2 = (const float*)d_in[10];
    const float* bih2 = (const float*)d_in[11];
    const float* bhh2 = (const float*)d_in[12];
    const float* wfc  = (const float*)d_in[13];
    const float* bfc  = (const float*)d_in[14];
    float* out = (float*)d_out;

    lstm_mfma<<<dim3(NBLK), dim3(NTH), 0, stream>>>(
        x, wih0, whh0, bih0, bhh0, wih1, whh1, bih1, bhh1,
        wih2, whh2, bih2, bhh2, wfc, bfc, out);
}

// Round 9
// 421.567 us; speedup vs baseline: 3304.9184x; 1.1139x over previous
//
#include <hip/hip_runtime.h>

// LSTM_61203283968689 — R15: R7 base (best: 344 µs) + stall-free trans placement.
// R14 (LDS-flag dataflow) regressed to 418: lag-1 deps quantize phase offsets to
// whole ticks (consumer starts when producer ENDS = zero stagger) + ~350cy poll
// overhead; MfmaUtil fell to 38.8. Reverted.
// In-order-issue model of R7's 1600cy tick: 854 MFMA drain + ew ~230 serial
// (3 waves in lockstep stall TOGETHER; a wave's issue is blocked through its
// dependent trans chain) + input-MFMA tail + ~400 handoff. R8/R10 regressed
// because sigm placed right after its producer MFMA stalls IMMEDIATELY (operand
// not complete) and blocks later independent MFMAs. R15 places each gate's sigm
// >=8 MFMA issues after its producer (completed ~150cy earlier) -> trans ops
// issue with ZERO stall and interleave into the MFMA drain on the VALU pipe
// (cross-wave co-issue is free, m114). Only the final c->h chain (~120cy) stays
// serial. Order pinned with sched_barrier(0) fences (R10 proved fences control
// emitted order). Per-gate accumulation order unchanged (bias, ih-lo, ih-hi,
// hh-lo, hh-hi) -> bit-identical output. Edge ticks (9/516) keep the R7 body.
// No setprio (R12: null). Layout/staging/82K LDS/diagonal as R7.

#define TT   512
#define NTH  768
#define NBLK 256

typedef _Float16 h16;
typedef __attribute__((ext_vector_type(8))) _Float16 h16x8;
typedef __attribute__((ext_vector_type(4))) float f32x4;

#define MFMA16(a, b, c) __builtin_amdgcn_mfma_f32_16x16x32_f16((a), (b), (c), 0, 0, 0)
#define FENCE() __builtin_amdgcn_sched_barrier(0)

__device__ __forceinline__ float sigm(float z) {
    return __builtin_amdgcn_rcpf(1.f + __expf(-z));
}

// B-fragment: 8 consecutive k of row `ro` from row-major W[.,ld], f32 -> f16.
__device__ __forceinline__ h16x8 loadB(const float* __restrict__ W, int ld, int ro,
                                       int k0, int kmax) {
    h16x8 r;
    #pragma unroll
    for (int i = 0; i < 8; ++i) {
        const int k = k0 + i;
        r[i] = (h16)((k < kmax) ? W[(size_t)ro * ld + k] : 0.f);
    }
    return r;
}

__global__ __attribute__((amdgpu_flat_work_group_size(NTH, NTH), amdgpu_waves_per_eu(3)))
void lstm_mfma(
    const float* __restrict__ x,
    const float* __restrict__ wih0, const float* __restrict__ whh0,
    const float* __restrict__ bih0, const float* __restrict__ bhh0,
    const float* __restrict__ wih1, const float* __restrict__ whh1,
    const float* __restrict__ bih1, const float* __restrict__ bhh1,
    const float* __restrict__ wih2, const float* __restrict__ whh2,
    const float* __restrict__ bih2, const float* __restrict__ bhh2,
    const float* __restrict__ wfc, const float* __restrict__ bfc,
    float* __restrict__ out)
{
    const int tid  = threadIdx.x;
    const int w    = tid >> 6;        // wave 0..11
    const int wl   = w >> 2;          // layer 0..2
    const int wg   = w & 3;           // gate-tile group: units [16wg, 16wg+16)
    const int lane = tid & 63;
    const int nloc = lane & 15;
    const int kg   = lane >> 4;       // k-group 0..3 ; also sample (C-row 4*kg)
    const int b4   = blockIdx.x * 4;
    const int u    = wg * 16 + nloc;

    // LDS: XL 64 KiB + HT 12 KiB + PAD 6 KiB = 82 KiB -> exactly 1 block/CU
    __shared__ alignas(16) h16 XL[2 * 32 * 512];
    __shared__ alignas(16) h16 HT[3 * 2 * 1024];
    __shared__ h16 PAD[3072];

    // ---------------- B fragments for THIS wave's layer only ----------------
    h16x8 Bf[4][4];
    float bias[4];
    #pragma unroll
    for (int g = 0; g < 4; ++g) {
        const int ro = g * 64 + u;
        if (wl == 0) {
            Bf[g][0] = loadB(wih0, 22, ro, kg * 8,      22);
            Bf[g][1] = loadB(whh0, 64, ro, kg * 8,      64);
            Bf[g][2] = loadB(whh0, 64, ro, 32 + kg * 8, 64);
            Bf[g][3] = Bf[g][2];
            bias[g]  = bih0[ro] + bhh0[ro];
        } else if (wl == 1) {
            Bf[g][0] = loadB(wih1, 64, ro, kg * 8,      64);
            Bf[g][1] = loadB(wih1, 64, ro, 32 + kg * 8, 64);
            Bf[g][2] = loadB(whh1, 64, ro, kg * 8,      64);
            Bf[g][3] = loadB(whh1, 64, ro, 32 + kg * 8, 64);
            bias[g]  = bih1[ro] + bhh1[ro];
        } else {
            Bf[g][0] = loadB(wih2, 64, ro, kg * 8,      64);
            Bf[g][1] = loadB(wih2, 64, ro, 32 + kg * 8, 64);
            Bf[g][2] = loadB(whh2, 64, ro, kg * 8,      64);
            Bf[g][3] = loadB(whh2, 64, ro, 32 + kg * 8, 64);
            bias[g]  = bih2[ro] + bhh2[ro];
        }
    }

    if (bias[0] > 1.0e30f) { PAD[tid & 2047] = (h16)bias[0]; out[0] = (float)PAD[0]; }

    // ---------------- zero LDS (pad rows must stay zero) ----------------
    {
        int* xz = (int*)XL;
        for (int i = tid; i < 2 * 32 * 256; i += NTH) xz[i] = 0;
        int* hz = (int*)HT;
        for (int i = tid; i < 3 * 2 * 512; i += NTH) hz[i] = 0;
    }
    __syncthreads();

    // ---------------- x staging ----------------
    auto stage_x = [&](int chunk) {
        if (tid < 4 * 22) {
            const int bl = tid / 22, ii = tid - bl * 22;
            const float* src = x + (size_t)(b4 + bl) * (22 * 512) + (size_t)ii * 512
                                 + chunk * 32;
            h16* dst = &XL[(chunk & 1) * (32 * 512) + (ii >> 3) * 128 + (4 * bl) * 8 + (ii & 7)];
            #pragma unroll
            for (int q = 0; q < 8; ++q) {
                const float4 v = ((const float4*)src)[q];
                dst[(q * 4 + 0) * 512] = (h16)v.x;
                dst[(q * 4 + 1) * 512] = (h16)v.y;
                dst[(q * 4 + 2) * 512] = (h16)v.z;
                dst[(q * 4 + 3) * 512] = (h16)v.w;
            }
        }
    };
    stage_x(0);

    const int lo8  = lane * 8;
    const int hoff = (u >> 3) * 128 + kg * 32 + (u & 7);

    float cst = 0.f;

    auto ew = [&](const f32x4& zi, const f32x4& zf, const f32x4& zg, const f32x4& zo,
                  h16* hb) {
        const float vi = sigm(zi[0]);
        const float vf = sigm(zf[0]);
        const float vg = 2.f * sigm(2.f * zg[0]) - 1.f;
        const float vo = sigm(zo[0]);
        const float c  = vf * cst + vi * vg;
        cst = c;
        hb[hoff] = (h16)(vo * (2.f * sigm(2.f * c) - 1.f));
    };

    f32x4 zb[4];
    #pragma unroll
    for (int g = 0; g < 4; ++g) zb[g] = f32x4{bias[g], 0.f, 0.f, 0.f};

    __syncthreads();

    // ---- prologue: zc carries bias + input-half of the NEXT step ----
    f32x4 zc[4];
    if (wl == 0) {
        const h16x8 ax0 = *(const h16x8*)&XL[lo8];
        #pragma unroll
        for (int g = 0; g < 4; ++g) zc[g] = MFMA16(ax0, Bf[g][0], zb[g]);
    } else {
        #pragma unroll
        for (int g = 0; g < 4; ++g) zc[g] = zb[g];
    }

    // ===================== EDGE tick (R7 body, 9/516 ticks) =====================
    auto tick_edge = [&](int t) {
        const int wb = t & 1, rb = wb ^ 1;
        const h16* h0r = HT + 0 * 2048 + rb * 1024;
        h16*       h0w = HT + 0 * 2048 + wb * 1024;
        const h16* h1r = HT + 1 * 2048 + rb * 1024;
        h16*       h1w = HT + 1 * 2048 + wb * 1024;
        const h16* h2r = HT + 2 * 2048 + rb * 1024;
        h16*       h2w = HT + 2 * 2048 + wb * 1024;

        if (wl == 0) {
            const bool sa = (t < TT);
            const bool ia = (t < TT - 1);
            f32x4 z[4];
            h16x8 a0lo, a0hi, axn;
            if (sa) {
                a0lo = *(const h16x8*)(h0r + lo8);
                a0hi = *(const h16x8*)(h0r + lo8 + 512);
            }
            if (ia) {
                const int tn = t + 1;
                axn = *(const h16x8*)&XL[((tn >> 5) & 1) * (32 * 512) + (tn & 31) * 512 + lo8];
            }
            if (sa) {
                #pragma unroll
                for (int g = 0; g < 4; ++g) {
                    z[g] = MFMA16(a0lo, Bf[g][1], zc[g]);
                    z[g] = MFMA16(a0hi, Bf[g][2], z[g]);
                }
            }
            if ((t & 31) == 16 && (t >> 5) < 15) stage_x((t >> 5) + 1);
            if (sa) ew(z[0], z[1], z[2], z[3], h0w);
            if (ia) {
                #pragma unroll
                for (int g = 0; g < 4; ++g)
                    zc[g] = MFMA16(axn, Bf[g][0], zb[g]);
            }
        } else if (wl == 1) {
            const bool sa = (t >= 2 && t < TT + 2);
            const bool ia = (t >= 1 && t < TT + 1);
            f32x4 z[4];
            h16x8 a1lo, a1hi, a0lo, a0hi;
            if (sa) {
                a1lo = *(const h16x8*)(h1r + lo8);
                a1hi = *(const h16x8*)(h1r + lo8 + 512);
            }
            if (ia) {
                a0lo = *(const h16x8*)(h0r + lo8);
                a0hi = *(const h16x8*)(h0r + lo8 + 512);
            }
            if (sa) {
                #pragma unroll
                for (int g = 0; g < 4; ++g) {
                    z[g] = MFMA16(a1lo, Bf[g][2], zc[g]);
                    z[g] = MFMA16(a1hi, Bf[g][3], z[g]);
                }
            }
            if (sa) ew(z[0], z[1], z[2], z[3], h1w);
            if (ia) {
                #pragma unroll
                for (int g = 0; g < 4; ++g) {
                    f32x4 zn = MFMA16(a0lo, Bf[g][0], zb[g]);
                    zc[g] = MFMA16(a0hi, Bf[g][1], zn);
                }
            }
        } else {
            const bool sa = (t >= 4);
            const bool ia = (t >= 3 && t < TT + 3);
            f32x4 z[4];
            h16x8 a2lo, a2hi, a1lo, a1hi;
            if (sa) {
                a2lo = *(const h16x8*)(h2r + lo8);
                a2hi = *(const h16x8*)(h2r + lo8 + 512);
            }
            if (ia) {
                a1lo = *(const h16x8*)(h1r + lo8);
                a1hi = *(const h16x8*)(h1r + lo8 + 512);
            }
            if (sa) {
                #pragma unroll
                for (int g = 0; g < 4; ++g) {
                    z[g] = MFMA16(a2lo, Bf[g][2], zc[g]);
                    z[g] = MFMA16(a2hi, Bf[g][3], z[g]);
                }
            }
            if (sa) ew(z[0], z[1], z[2], z[3], h2w);
            if (ia) {
                #pragma unroll
                for (int g = 0; g < 4; ++g) {
                    f32x4 zn = MFMA16(a1lo, Bf[g][0], zb[g]);
                    zc[g] = MFMA16(a1hi, Bf[g][1], zn);
                }
            }
        }
        __syncthreads();
    };

    // ==== STEADY tick: stall-free trans placement, pinned with sched_barrier(0) ====
    // Each sigm is placed >=8 MFMA issues after its producer (complete -> no
    // scoreboard stall); trans issues interleave into the MFMA drain. Only the
    // final c->h chain is serial.
    auto tick_steady = [&](int t) {
        const int wb = t & 1, rb = wb ^ 1;
        const h16* h0r = HT + 0 * 2048 + rb * 1024;
        h16*       h0w = HT + 0 * 2048 + wb * 1024;
        const h16* h1r = HT + 1 * 2048 + rb * 1024;
        h16*       h1w = HT + 1 * 2048 + wb * 1024;
        const h16* h2r = HT + 2 * 2048 + rb * 1024;
        h16*       h2w = HT + 2 * 2048 + wb * 1024;

        if (wl == 0) {           // L0: self step t, input-prefetch x(t+1)
            const h16x8 a0lo = *(const h16x8*)(h0r + lo8);
            const h16x8 a0hi = *(const h16x8*)(h0r + lo8 + 512);
            const int tn = t + 1;
            const h16x8 axn  = *(const h16x8*)&XL[((tn >> 5) & 1) * (32 * 512)
                                                  + (tn & 31) * 512 + lo8];
            FENCE();
            f32x4 z0 = MFMA16(a0lo, Bf[0][1], zc[0]); z0 = MFMA16(a0hi, Bf[0][2], z0);
            f32x4 z1 = MFMA16(a0lo, Bf[1][1], zc[1]); z1 = MFMA16(a0hi, Bf[1][2], z1);
            zc[0] = MFMA16(axn, Bf[0][0], zb[0]);
            zc[1] = MFMA16(axn, Bf[1][0], zb[1]);
            FENCE();
            const float vi = sigm(z0[0]);           // z0 completed ~4 MFMAs ago
            FENCE();
            f32x4 z2 = MFMA16(a0lo, Bf[2][1], zc[2]); z2 = MFMA16(a0hi, Bf[2][2], z2);
            f32x4 z3 = MFMA16(a0lo, Bf[3][1], zc[3]); z3 = MFMA16(a0hi, Bf[3][2], z3);
            FENCE();
            const float vf = sigm(z1[0]);
            FENCE();
            zc[2] = MFMA16(axn, Bf[2][0], zb[2]);
            zc[3] = MFMA16(axn, Bf[3][0], zb[3]);
            FENCE();
            const float vg = 2.f * sigm(2.f * z2[0]) - 1.f;
            const float vo = sigm(z3[0]);
            const float c  = vf * cst + vi * vg;
            cst = c;
            h0w[hoff] = (h16)(vo * (2.f * sigm(2.f * c) - 1.f));
            if ((t & 31) == 16 && (t >> 5) < 15) stage_x((t >> 5) + 1);
        } else if (wl == 1) {    // L1: self step t-2, input-prefetch t-1
            const h16x8 a1lo = *(const h16x8*)(h1r + lo8);
            const h16x8 a1hi = *(const h16x8*)(h1r + lo8 + 512);
            const h16x8 a0lo = *(const h16x8*)(h0r + lo8);
            const h16x8 a0hi = *(const h16x8*)(h0r + lo8 + 512);
            FENCE();
            f32x4 z0 = MFMA16(a1lo, Bf[0][2], zc[0]); z0 = MFMA16(a1hi, Bf[0][3], z0);
            f32x4 z1 = MFMA16(a1lo, Bf[1][2], zc[1]); z1 = MFMA16(a1hi, Bf[1][3], z1);
            { f32x4 zn = MFMA16(a0lo, Bf[0][0], zb[0]); zc[0] = MFMA16(a0hi, Bf[0][1], zn); }
            { f32x4 zn = MFMA16(a0lo, Bf[1][0], zb[1]); zc[1] = MFMA16(a0hi, Bf[1][1], zn); }
            FENCE();
            const float vi = sigm(z0[0]);           // z0 completed ~6 MFMAs ago
            FENCE();
            f32x4 z2 = MFMA16(a1lo, Bf[2][2], zc[2]); z2 = MFMA16(a1hi, Bf[2][3], z2);
            f32x4 z3 = MFMA16(a1lo, Bf[3][2], zc[3]); z3 = MFMA16(a1hi, Bf[3][3], z3);
            FENCE();
            const float vf = sigm(z1[0]);
            FENCE();
            { f32x4 zn = MFMA16(a0lo, Bf[2][0], zb[2]); zc[2] = MFMA16(a0hi, Bf[2][1], zn); }
            { f32x4 zn = MFMA16(a0lo, Bf[3][0], zb[3]); zc[3] = MFMA16(a0hi, Bf[3][1], zn); }
            FENCE();
            const float vg = 2.f * sigm(2.f * z2[0]) - 1.f;
            const float vo = sigm(z3[0]);
            const float c  = vf * cst + vi * vg;
            cst = c;
            h1w[hoff] = (h16)(vo * (2.f * sigm(2.f * c) - 1.f));
        } else {                 // L2: self step t-4, input-prefetch t-3
            const h16x8 a2lo = *(const h16x8*)(h2r + lo8);
            const h16x8 a2hi = *(const h16x8*)(h2r + lo8 + 512);
            const h16x8 a1lo = *(const h16x8*)(h1r + lo8);
            const h16x8 a1hi = *(const h16x8*)(h1r + lo8 + 512);
            FENCE();
            f32x4 z0 = MFMA16(a2lo, Bf[0][2], zc[0]); z0 = MFMA16(a2hi, Bf[0][3], z0);
            f32x4 z1 = MFMA16(a2lo, Bf[1][2], zc[1]); z1 = MFMA16(a2hi, Bf[1][3], z1);
            { f32x4 zn = MFMA16(a1lo, Bf[0][0], zb[0]); zc[0] = MFMA16(a1hi, Bf[0][1], zn); }
            { f32x4 zn = MFMA16(a1lo, Bf[1][0], zb[1]); zc[1] = MFMA16(a1hi, Bf[1][1], zn); }
            FENCE();
            const float vi = sigm(z0[0]);
            FENCE();
            f32x4 z2 = MFMA16(a2lo, Bf[2][2], zc[2]); z2 = MFMA16(a2hi, Bf[2][3], z2);
            f32x4 z3 = MFMA16(a2lo, Bf[3][2], zc[3]); z3 = MFMA16(a2hi, Bf[3][3], z3);
            FENCE();
            const float vf = sigm(z1[0]);
            FENCE();
            { f32x4 zn = MFMA16(a1lo, Bf[2][0], zb[2]); zc[2] = MFMA16(a1hi, Bf[2][1], zn); }
            { f32x4 zn = MFMA16(a1lo, Bf[3][0], zb[3]); zc[3] = MFMA16(a1hi, Bf[3][1], zn); }
            FENCE();
            const float vg = 2.f * sigm(2.f * z2[0]) - 1.f;
            const float vo = sigm(z3[0]);
            const float c  = vf * cst + vi * vg;
            cst = c;
            h2w[hoff] = (h16)(vo * (2.f * sigm(2.f * c) - 1.f));
        }
        __syncthreads();
    };

    #pragma unroll 1
    for (int t = 0; t < 4; ++t) tick_edge(t);
    #pragma unroll 1
    for (int t = 4; t < TT - 1; ++t) tick_steady(t);
    #pragma unroll 1
    for (int t = TT - 1; t < TT + 4; ++t) tick_edge(t);

    // ------------- FC epilogue: h2(step 511) in buffer (TT+1)&1 = 1 -----------
    if (tid < 16) {
        const int ms = tid >> 2, o = tid & 3;
        const h16* h2 = HT + 2 * 2048 + 1024;
        float acc = bfc[o];
        #pragma unroll 1
        for (int uu = 0; uu < 64; ++uu)
            acc += (float)h2[(uu >> 3) * 128 + (4 * ms) * 8 + (uu & 7)] * wfc[o * 64 + uu];
        out[(b4 + ms) * 4 + o] = acc;
    }
}

extern "C" void kernel_launch(void* const* d_in, const int* in_sizes, int n_in,
                              void* d_out, int out_size, void* d_ws, size_t ws_size,
                              hipStream_t stream) {
    const float* x    = (const float*)d_in[0];
    const float* wih0 = (const float*)d_in[1];
    const float* whh0 = (const float*)d_in[2];
    const float* bih0 = (const float*)d_in[3];
    const float* bhh0 = (const float*)d_in[4];
    const float* wih1 = (const float*)d_in[5];
    const float* whh1 = (const float*)d_in[6];
    const float* bih1 = (const float*)d_in[7];
    const float* bhh1 = (const float*)d_in[8];
    const float* wih2 = (const float*)d_in[9];
    const float* whh2 = (const float*)d_in[10];
    const float* bih2 = (const float*)d_in[11];
    const float* bhh2 = (const float*)d_in[12];
    const float* wfc  = (const float*)d_in[13];
    const float* bfc  = (const float*)d_in[14];
    float* out = (float*)d_out;

    lstm_mfma<<<dim3(NBLK), dim3(NTH), 0, stream>>>(
        x, wih0, whh0, bih0, bhh0, wih1, whh1, bih1, bhh1,
        wih2, whh2, bih2, bhh2, wfc, bfc, out);
}

// Round 10
// 418.588 us; speedup vs baseline: 3328.4363x; 1.0071x over previous
//
#include <hip/hip_runtime.h>

// LSTM_61203283968689 — R16: R7 structure (best: 344 µs) + PACKED LDS tiles +
// 16-lane exec-masked A-fragment reads. Residual analysis: tick 1600 = 854 MFMA
// + ~750 residual; the head is an LDS read burst of 44-48 ds_read_b128 x ~12cy
// (m134: LDS service is volume-proportional, ~85B/cy) ~= 550-580cy serial.
// 3/4 of that volume is PAD: A-frag rows are lane&15, real samples occupy rows
// {0,4,8,12} -> only lanes with lane&3==0 carry data. R16 packs tiles to 4 real
// rows (h: [4][72] h16, x: [4][40], 16B-aligned strides, bank-spread) and reads
// under a 16-lane mask: 1KB -> 256B per read (~3cy). Pad-lane frag registers
// hold garbage — harmless: MFMA rows are independent, garbage stays in pad
// C-rows never read (ew reads reg0 = row 4*kg, always real). Frags are
// persistent zero-init wave state (no per-tick movs, no UB). Math on real rows
// identical (bias, ih-lo, ih-hi, hh-lo, hh-hi per gate) -> absmax unchanged.
// Scheduling experiments (SGB/fences/setprio/flags, R8-R15) all >= 344 -> the
// compiler's natural R7 schedule is kept verbatim.
// LDS: XL 20K + HT 3.4K + PAD 60K ~= 83.4 KiB -> 1 block/CU.

#define TT   512
#define NTH  768
#define NBLK 256

#define XSTR  40            // x row stride (h16), 80B, 16B-aligned
#define XSLAB (4 * XSTR)    // 160 h16 per t
#define XCH   (32 * XSLAB)  // 5120 h16 per chunk
#define HSTR  72            // h row stride (h16), 144B, 16B-aligned
#define HBUF  (4 * HSTR)    // 288 h16 per buffer
#define HLAY  (2 * HBUF)    // 576 h16 per layer

typedef _Float16 h16;
typedef __attribute__((ext_vector_type(8))) _Float16 h16x8;
typedef __attribute__((ext_vector_type(4))) float f32x4;

#define MFMA16(a, b, c) __builtin_amdgcn_mfma_f32_16x16x32_f16((a), (b), (c), 0, 0, 0)

__device__ __forceinline__ float sigm(float z) {
    return __builtin_amdgcn_rcpf(1.f + __expf(-z));
}

// B-fragment: 8 consecutive k of row `ro` from row-major W[.,ld], f32 -> f16.
__device__ __forceinline__ h16x8 loadB(const float* __restrict__ W, int ld, int ro,
                                       int k0, int kmax) {
    h16x8 r;
    #pragma unroll
    for (int i = 0; i < 8; ++i) {
        const int k = k0 + i;
        r[i] = (h16)((k < kmax) ? W[(size_t)ro * ld + k] : 0.f);
    }
    return r;
}

struct TrueC  { static constexpr bool value = true;  };
struct FalseC { static constexpr bool value = false; };

__global__ __attribute__((amdgpu_flat_work_group_size(NTH, NTH), amdgpu_waves_per_eu(3)))
void lstm_mfma(
    const float* __restrict__ x,
    const float* __restrict__ wih0, const float* __restrict__ whh0,
    const float* __restrict__ bih0, const float* __restrict__ bhh0,
    const float* __restrict__ wih1, const float* __restrict__ whh1,
    const float* __restrict__ bih1, const float* __restrict__ bhh1,
    const float* __restrict__ wih2, const float* __restrict__ whh2,
    const float* __restrict__ bih2, const float* __restrict__ bhh2,
    const float* __restrict__ wfc, const float* __restrict__ bfc,
    float* __restrict__ out)
{
    const int tid  = threadIdx.x;
    const int w    = tid >> 6;        // wave 0..11
    const int wl   = w >> 2;          // layer 0..2
    const int wg   = w & 3;           // gate-tile group: units [16wg, 16wg+16)
    const int lane = tid & 63;
    const int nloc = lane & 15;       // unit-local index
    const int kg   = lane >> 4;       // sample (C-row 4*kg)
    const int b4   = blockIdx.x * 4;
    const int u    = wg * 16 + nloc;  // this lane's hidden unit

    // LDS: XL 20 KiB + HT 3.4 KiB + PAD 60 KiB ~= 83.4 KiB -> 1 block/CU
    __shared__ alignas(16) h16 XL[2 * XCH];   // x: [2 chunks][32 t][4 samp][40 k]
    __shared__ alignas(16) h16 HT[3 * HLAY];  // h: [3 layer][2 buf][4 samp][72 u]
    __shared__ h16 PAD[30720];                // occupancy limiter (kept alive)

    // ---------------- B fragments for THIS wave's layer only ----------------
    h16x8 Bf[4][4];
    float bias[4];
    #pragma unroll
    for (int g = 0; g < 4; ++g) {
        const int ro = g * 64 + u;
        if (wl == 0) {
            Bf[g][0] = loadB(wih0, 22, ro, kg * 8,      22);
            Bf[g][1] = loadB(whh0, 64, ro, kg * 8,      64);
            Bf[g][2] = loadB(whh0, 64, ro, 32 + kg * 8, 64);
            Bf[g][3] = Bf[g][2];
            bias[g]  = bih0[ro] + bhh0[ro];
        } else if (wl == 1) {
            Bf[g][0] = loadB(wih1, 64, ro, kg * 8,      64);
            Bf[g][1] = loadB(wih1, 64, ro, 32 + kg * 8, 64);
            Bf[g][2] = loadB(whh1, 64, ro, kg * 8,      64);
            Bf[g][3] = loadB(whh1, 64, ro, 32 + kg * 8, 64);
            bias[g]  = bih1[ro] + bhh1[ro];
        } else {
            Bf[g][0] = loadB(wih2, 64, ro, kg * 8,      64);
            Bf[g][1] = loadB(wih2, 64, ro, 32 + kg * 8, 64);
            Bf[g][2] = loadB(whh2, 64, ro, kg * 8,      64);
            Bf[g][3] = loadB(whh2, 64, ro, 32 + kg * 8, 64);
            bias[g]  = bih2[ro] + bhh2[ro];
        }
    }

    // keep PAD alive (condition can never be true at runtime)
    if (bias[0] > 1.0e30f) { PAD[tid & 2047] = (h16)bias[0]; out[0] = (float)PAD[0]; }

    // ---------------- zero LDS (x k-pad 22..31 must stay zero; h(-1)=0) --------
    {
        int* xz = (int*)XL;
        for (int i = tid; i < XCH; i += NTH) xz[i] = 0;          // 2*XCH h16 = XCH ints
        int* hz = (int*)HT;
        for (int i = tid; i < (3 * HLAY) / 2; i += NTH) hz[i] = 0;
    }
    __syncthreads();

    // ---------------- x staging: [chunk][t][sample][k] packed ----------------
    auto stage_x = [&](int chunk) {
        if (tid < 4 * 22) {
            const int bl = tid / 22, ii = tid - bl * 22;
            const float* src = x + (size_t)(b4 + bl) * (22 * 512) + (size_t)ii * 512
                                 + chunk * 32;
            h16* dst = &XL[(chunk & 1) * XCH + bl * XSTR + ii];
            #pragma unroll
            for (int q = 0; q < 8; ++q) {
                const float4 v = ((const float4*)src)[q];
                dst[(q * 4 + 0) * XSLAB] = (h16)v.x;
                dst[(q * 4 + 1) * XSLAB] = (h16)v.y;
                dst[(q * 4 + 2) * XSLAB] = (h16)v.z;
                dst[(q * 4 + 3) * XSLAB] = (h16)v.w;
            }
        }
    };
    stage_x(0);

    // ---------------- per-lane constants ----------------
    const int j     = lane >> 2;                  // active-lane index (lane&3==0)
    const int hro   = (j & 3) * HSTR + (j >> 2) * 8;  // packed h-tile read offset
    const int xro   = (j & 3) * XSTR + (j >> 2) * 8;  // packed x-slab read offset
    const int hoffp = kg * HSTR + u;              // h-write: [sample][unit]

    float cst = 0.f;

    auto ew = [&](const f32x4& zi, const f32x4& zf, const f32x4& zg, const f32x4& zo,
                  h16* hb) {
        const float vi = sigm(zi[0]);
        const float vf = sigm(zf[0]);
        const float vg = 2.f * sigm(2.f * zg[0]) - 1.f;
        const float vo = sigm(zo[0]);
        const float c  = vf * cst + vi * vg;
        cst = c;
        hb[hoffp] = (h16)(vo * (2.f * sigm(2.f * c) - 1.f));
    };

    // gate-bias C fragments
    f32x4 zb[4];
    #pragma unroll
    for (int g = 0; g < 4; ++g) zb[g] = f32x4{bias[g], 0.f, 0.f, 0.f};

    // persistent A-fragments (zero-init once; only lanes lane&3==0 ever load —
    // pad-lane contents are don't-care, contained in pad C-rows)
    h16x8 fx = {};                 // L0: x(t+1) input frag
    h16x8 fslo = {}, fshi = {};    // self-layer h lo/hi
    h16x8 fulo = {}, fuhi = {};    // upstream-layer h lo/hi (L1/L2)

    __syncthreads();

    // ---- prologue: zc carries bias + input-half contribution of the NEXT step ----
    f32x4 zc[4];
    if (wl == 0) {
        if ((lane & 3) == 0) fx = *(const h16x8*)&XL[xro];   // chunk 0, t=0
        #pragma unroll
        for (int g = 0; g < 4; ++g) zc[g] = MFMA16(fx, Bf[g][0], zb[g]);
    } else {
        #pragma unroll
        for (int g = 0; g < 4; ++g) zc[g] = zb[g];
    }

    // ============================ diagonal tick loop ============================
    auto tick = [&](int t, auto edgec) {
        constexpr bool EDGE = decltype(edgec)::value;
        const int wb = t & 1, rb = wb ^ 1;
        const h16* h0r = HT + 0 * HLAY + rb * HBUF;
        h16*       h0w = HT + 0 * HLAY + wb * HBUF;
        const h16* h1r = HT + 1 * HLAY + rb * HBUF;
        h16*       h1w = HT + 1 * HLAY + wb * HBUF;
        const h16* h2r = HT + 2 * HLAY + rb * HBUF;
        h16*       h2w = HT + 2 * HLAY + wb * HBUF;

        if (wl == 0) {           // -------- L0: self for step t, x-prefetch t+1 ------
            const bool sa = !EDGE || (t < TT);
            const bool ia = !EDGE || (t < TT - 1);
            f32x4 z[4];
            if ((lane & 3) == 0) {
                if (sa) {
                    fslo = *(const h16x8*)(h0r + hro);
                    fshi = *(const h16x8*)(h0r + hro + 32);
                }
                if (ia) {
                    const int tn = t + 1;
                    fx = *(const h16x8*)&XL[((tn >> 5) & 1) * XCH + (tn & 31) * XSLAB + xro];
                }
            }
            if (sa) {
                #pragma unroll
                for (int g = 0; g < 4; ++g) {
                    z[g] = MFMA16(fslo, Bf[g][1], zc[g]);
                    z[g] = MFMA16(fshi, Bf[g][2], z[g]);
                }
            }
            if ((t & 31) == 16 && (t >> 5) < 15) stage_x((t >> 5) + 1);
            if (sa) ew(z[0], z[1], z[2], z[3], h0w);
            if (ia) {
                #pragma unroll
                for (int g = 0; g < 4; ++g)
                    zc[g] = MFMA16(fx, Bf[g][0], zb[g]);
            }
        } else if (wl == 1) {    // ---- L1: self for step t-2, input-prefetch t-1 ----
            const bool sa = !EDGE || (t >= 2 && t < TT + 2);
            const bool ia = !EDGE || (t >= 1 && t < TT + 1);
            f32x4 z[4];
            if ((lane & 3) == 0) {
                if (sa) {
                    fslo = *(const h16x8*)(h1r + hro);
                    fshi = *(const h16x8*)(h1r + hro + 32);
                }
                if (ia) {
                    fulo = *(const h16x8*)(h0r + hro);
                    fuhi = *(const h16x8*)(h0r + hro + 32);
                }
            }
            if (sa) {
                #pragma unroll
                for (int g = 0; g < 4; ++g) {
                    z[g] = MFMA16(fslo, Bf[g][2], zc[g]);
                    z[g] = MFMA16(fshi, Bf[g][3], z[g]);
                }
            }
            if (sa) ew(z[0], z[1], z[2], z[3], h1w);
            if (ia) {
                #pragma unroll
                for (int g = 0; g < 4; ++g) {
                    f32x4 zn = MFMA16(fulo, Bf[g][0], zb[g]);
                    zc[g] = MFMA16(fuhi, Bf[g][1], zn);
                }
            }
        } else {                 // ------ L2: self for step t-4, input-prefetch t-3 ------
            const bool sa = !EDGE || (t >= 4);
            const bool ia = !EDGE || (t >= 3 && t < TT + 3);
            f32x4 z[4];
            if ((lane & 3) == 0) {
                if (sa) {
                    fslo = *(const h16x8*)(h2r + hro);
                    fshi = *(const h16x8*)(h2r + hro + 32);
                }
                if (ia) {
                    fulo = *(const h16x8*)(h1r + hro);
                    fuhi = *(const h16x8*)(h1r + hro + 32);
                }
            }
            if (sa) {
                #pragma unroll
                for (int g = 0; g < 4; ++g) {
                    z[g] = MFMA16(fslo, Bf[g][2], zc[g]);
                    z[g] = MFMA16(fshi, Bf[g][3], z[g]);
                }
            }
            if (sa) ew(z[0], z[1], z[2], z[3], h2w);
            if (ia) {
                #pragma unroll
                for (int g = 0; g < 4; ++g) {
                    f32x4 zn = MFMA16(fulo, Bf[g][0], zb[g]);
                    zc[g] = MFMA16(fuhi, Bf[g][1], zn);
                }
            }
        }

        __syncthreads();
    };

    #pragma unroll 1
    for (int t = 0; t < 4; ++t) tick(t, TrueC{});
    #pragma unroll 1
    for (int t = 4; t < TT - 1; ++t) tick(t, FalseC{});     // branch-free steady state
    #pragma unroll 1
    for (int t = TT - 1; t < TT + 4; ++t) tick(t, TrueC{});

    // ------------- FC epilogue: h2(step 511) in buffer (TT+1)&1 = 1 -----------
    if (tid < 16) {
        const int ms = tid >> 2, o = tid & 3;
        const h16* h2 = HT + 2 * HLAY + 1 * HBUF;
        float acc = bfc[o];
        #pragma unroll 1
        for (int uu = 0; uu < 64; ++uu)
            acc += (float)h2[ms * HSTR + uu] * wfc[o * 64 + uu];
        out[(b4 + ms) * 4 + o] = acc;
    }
}

extern "C" void kernel_launch(void* const* d_in, const int* in_sizes, int n_in,
                              void* d_out, int out_size, void* d_ws, size_t ws_size,
                              hipStream_t stream) {
    const float* x    = (const float*)d_in[0];
    const float* wih0 = (const float*)d_in[1];
    const float* whh0 = (const float*)d_in[2];
    const float* bih0 = (const float*)d_in[3];
    const float* bhh0 = (const float*)d_in[4];
    const float* wih1 = (const float*)d_in[5];
    const float* whh1 = (const float*)d_in[6];
    const float* bih1 = (const float*)d_in[7];
    const float* bhh1 = (const float*)d_in[8];
    const float* wih2 = (const float*)d_in[9];
    const float* whh2 = (const float*)d_in[10];
    const float* bih2 = (const float*)d_in[11];
    const float* bhh2 = (const float*)d_in[12];
    const float* wfc  = (const float*)d_in[13];
    const float* bfc  = (const float*)d_in[14];
    float* out = (float*)d_out;

    lstm_mfma<<<dim3(NBLK), dim3(NTH), 0, stream>>>(
        x, wih0, whh0, bih0, bhh0, wih1, whh1, bih1, bhh1,
        wih2, whh2, bih2, bhh2, wfc, bfc, out);
}

// Round 11
// 380.494 us; speedup vs baseline: 3661.6681x; 1.1001x over previous
//
#include <hip/hip_runtime.h>

// LSTM_61203283968689 — R17: R7 base (best: 344 µs) + TRANS-PIPE REDUCTION.
// R8-R16 bracket: MfmaUtil+VALUBusy ~= 93% under every scheduling/sync/LDS
// variant -> matrix-pipe and VALU-pipe times are ADDITIVE on a SIMD here.
// Tick 1600 = 750 MFMA + 749 VALU + ~100 barrier. VALU fit: 10 trans/wave
// x 16cy x 3 waves = 480cy = 2/3 of the VALU term -> shrink trans count.
// (1) Weights/biases pre-scaled by -log2e (g gate: -2log2e) at frag load:
//     every exp(-z) becomes a bare v_exp_f32 (exp2), no argument mul.
//     f16 quantization is scale-invariant (same relative 2^-11 grid).
// (2) Shared-denominator fusion (algebraically exact):
//     c = [c*(1+ei)(1+eg) + (1-eg)(1+ef)] * rcp((1+ef)(1+ei)(1+eg))
//     h = (1-ec) * rcp((1+ec)(1+eo)),  ec = exp2(clamp(-2log2e*c, <=126))
//     5 rcp -> 2 rcp. Trans 10 -> 7 per wave (-144 cy/SIMD/tick).
// Overflow audit: |z_scaled|<=~46 -> exp2 finite; products <= e^64 < f32 max;
// only e_c can overflow (|c|>44) -> fminf clamp 126 saturates gracefully.
// Everything else EXACT R7 (R16's packed-LDS reverted: 357 > 344).

#define TT   512
#define NTH  768
#define NBLK 256

typedef _Float16 h16;
typedef __attribute__((ext_vector_type(8))) _Float16 h16x8;
typedef __attribute__((ext_vector_type(4))) float f32x4;

#define MFMA16(a, b, c) __builtin_amdgcn_mfma_f32_16x16x32_f16((a), (b), (c), 0, 0, 0)

#define NLOG2E  -1.4426950408889634f   // -log2(e)
#define N2LOG2E -2.8853900817779268f   // -2*log2(e)

// B-fragment: 8 consecutive k of row `ro` from row-major W[.,ld], f32 -> f16,
// pre-scaled so MFMA emits z' = scale*z and exp2(z') = exp(-z) / exp(-2z).
__device__ __forceinline__ h16x8 loadB(const float* __restrict__ W, int ld, int ro,
                                       int k0, int kmax, float scale) {
    h16x8 r;
    #pragma unroll
    for (int i = 0; i < 8; ++i) {
        const int k = k0 + i;
        r[i] = (h16)((k < kmax) ? scale * W[(size_t)ro * ld + k] : 0.f);
    }
    return r;
}

struct TrueC  { static constexpr bool value = true;  };
struct FalseC { static constexpr bool value = false; };

__global__ __attribute__((amdgpu_flat_work_group_size(NTH, NTH), amdgpu_waves_per_eu(3)))
void lstm_mfma(
    const float* __restrict__ x,
    const float* __restrict__ wih0, const float* __restrict__ whh0,
    const float* __restrict__ bih0, const float* __restrict__ bhh0,
    const float* __restrict__ wih1, const float* __restrict__ whh1,
    const float* __restrict__ bih1, const float* __restrict__ bhh1,
    const float* __restrict__ wih2, const float* __restrict__ whh2,
    const float* __restrict__ bih2, const float* __restrict__ bhh2,
    const float* __restrict__ wfc, const float* __restrict__ bfc,
    float* __restrict__ out)
{
    const int tid  = threadIdx.x;
    const int w    = tid >> 6;        // wave 0..11
    const int wl   = w >> 2;          // layer 0..2
    const int wg   = w & 3;           // gate-tile group: units [16wg, 16wg+16)
    const int lane = tid & 63;
    const int nloc = lane & 15;       // unit-local index / B-frag col
    const int kg   = lane >> 4;       // k-group 0..3 ; also sample (C-row 4*kg)
    const int b4   = blockIdx.x * 4;
    const int u    = wg * 16 + nloc;  // this lane's hidden unit

    // LDS: XL 64 KiB + HT 12 KiB + PAD 6 KiB = 82 KiB -> exactly 1 block/CU
    __shared__ alignas(16) h16 XL[2 * 32 * 512];   // x, 2 chunks x 32 t x frag-tile(512)
    __shared__ alignas(16) h16 HT[3 * 2 * 1024];   // h[layer][pp] frag-tiles
    __shared__ h16 PAD[3072];                      // occupancy limiter (kept alive below)

    // ---------------- B fragments for THIS wave's layer only ----------------
    // Gate order i,f,g,o (PyTorch rows g*64..): scale g-gate by -2log2e, rest -log2e.
    h16x8 Bf[4][4];
    float bias[4];
    #pragma unroll
    for (int g = 0; g < 4; ++g) {
        const int ro = g * 64 + u;                  // original row (i,f,g,o blocks)
        const float sc = (g == 2) ? N2LOG2E : NLOG2E;
        if (wl == 0) {
            Bf[g][0] = loadB(wih0, 22, ro, kg * 8,      22, sc);
            Bf[g][1] = loadB(whh0, 64, ro, kg * 8,      64, sc);
            Bf[g][2] = loadB(whh0, 64, ro, 32 + kg * 8, 64, sc);
            Bf[g][3] = Bf[g][2];
            bias[g]  = sc * (bih0[ro] + bhh0[ro]);
        } else if (wl == 1) {
            Bf[g][0] = loadB(wih1, 64, ro, kg * 8,      64, sc);
            Bf[g][1] = loadB(wih1, 64, ro, 32 + kg * 8, 64, sc);
            Bf[g][2] = loadB(whh1, 64, ro, kg * 8,      64, sc);
            Bf[g][3] = loadB(whh1, 64, ro, 32 + kg * 8, 64, sc);
            bias[g]  = sc * (bih1[ro] + bhh1[ro]);
        } else {
            Bf[g][0] = loadB(wih2, 64, ro, kg * 8,      64, sc);
            Bf[g][1] = loadB(wih2, 64, ro, 32 + kg * 8, 64, sc);
            Bf[g][2] = loadB(whh2, 64, ro, kg * 8,      64, sc);
            Bf[g][3] = loadB(whh2, 64, ro, 32 + kg * 8, 64, sc);
            bias[g]  = sc * (bih2[ro] + bhh2[ro]);
        }
    }

    // keep PAD alive (condition can never be true at runtime)
    if (bias[0] > 1.0e30f) { PAD[tid & 2047] = (h16)bias[0]; out[0] = (float)PAD[0]; }

    // ---------------- zero LDS (pad rows must stay zero) ----------------
    {
        int* xz = (int*)XL;
        for (int i = tid; i < 2 * 32 * 256; i += NTH) xz[i] = 0;
        int* hz = (int*)HT;
        for (int i = tid; i < 3 * 2 * 512; i += NTH) hz[i] = 0;
    }
    __syncthreads();

    // ---------------- x staging: sample bl -> A-row 4*bl, frag layout ------------
    auto stage_x = [&](int chunk) {
        if (tid < 4 * 22) {
            const int bl = tid / 22, ii = tid - bl * 22;
            const float* src = x + (size_t)(b4 + bl) * (22 * 512) + (size_t)ii * 512
                                 + chunk * 32;
            h16* dst = &XL[(chunk & 1) * (32 * 512) + (ii >> 3) * 128 + (4 * bl) * 8 + (ii & 7)];
            #pragma unroll
            for (int q = 0; q < 8; ++q) {
                const float4 v = ((const float4*)src)[q];
                dst[(q * 4 + 0) * 512] = (h16)v.x;
                dst[(q * 4 + 1) * 512] = (h16)v.y;
                dst[(q * 4 + 2) * 512] = (h16)v.z;
                dst[(q * 4 + 3) * 512] = (h16)v.w;
            }
        }
    };
    stage_x(0);

    // ---------------- per-lane constants ----------------
    const int lo8  = lane * 8;                           // A-frag offset (h16 units)
    const int hoff = (u >> 3) * 128 + kg * 32 + (u & 7); // h-write: row 4*kg, unit u

    float cst = 0.f;

    // ew: 7 trans (5 exp2 + 2 rcp), fused denominators. z' are pre-scaled so
    // exp2(z') = exp(-z) (i,f,o) / exp(-2z) (g).
    auto ew = [&](const f32x4& zi, const f32x4& zf, const f32x4& zg, const f32x4& zo,
                  h16* hb) {
        const float ei = __builtin_amdgcn_exp2f(zi[0]);   // exp(-z_i)
        const float ef = __builtin_amdgcn_exp2f(zf[0]);   // exp(-z_f)
        const float eg = __builtin_amdgcn_exp2f(zg[0]);   // exp(-2 z_g)
        const float eo = __builtin_amdgcn_exp2f(zo[0]);   // exp(-z_o)
        const float pig = (1.f + ei) * (1.f + eg);
        const float pf  = 1.f + ef;
        const float n   = cst * pig + (1.f - eg) * pf;
        const float c   = n * __builtin_amdgcn_rcpf(pf * pig);
        cst = c;
        const float ea  = fminf(c * N2LOG2E, 126.f);      // overflow guard (|c|>44)
        const float ec  = __builtin_amdgcn_exp2f(ea);     // exp(-2c)
        const float h   = (1.f - ec)
                        * __builtin_amdgcn_rcpf((1.f + ec) * (1.f + eo));
        hb[hoff] = (h16)h;
    };

    // gate-bias C fragments (read-only; MFMA C-in by value, so zero movs/tick)
    f32x4 zb[4];
    #pragma unroll
    for (int g = 0; g < 4; ++g) zb[g] = f32x4{bias[g], 0.f, 0.f, 0.f};

    __syncthreads();

    // ---- prologue: zc carries bias + input-half contribution of the NEXT step ----
    f32x4 zc[4];
    if (wl == 0) {
        const h16x8 ax0 = *(const h16x8*)&XL[lo8];   // chunk 0, t=0
        #pragma unroll
        for (int g = 0; g < 4; ++g) zc[g] = MFMA16(ax0, Bf[g][0], zb[g]);
    } else {
        #pragma unroll
        for (int g = 0; g < 4; ++g) zc[g] = zb[g];
    }

    // ============================ diagonal tick loop ============================
    auto tick = [&](int t, auto edgec) {
        constexpr bool EDGE = decltype(edgec)::value;
        const int wb = t & 1, rb = wb ^ 1;
        const h16* h0r = HT + 0 * 2048 + rb * 1024;
        h16*       h0w = HT + 0 * 2048 + wb * 1024;
        const h16* h1r = HT + 1 * 2048 + rb * 1024;
        h16*       h1w = HT + 1 * 2048 + wb * 1024;
        const h16* h2r = HT + 2 * 2048 + rb * 1024;
        h16*       h2w = HT + 2 * 2048 + wb * 1024;

        if (wl == 0) {           // -------- L0: self for step t, x-prefetch t+1 ------
            const bool sa = !EDGE || (t < TT);
            const bool ia = !EDGE || (t < TT - 1);
            f32x4 z[4];
            h16x8 a0lo, a0hi, axn;
            if (sa) {
                a0lo = *(const h16x8*)(h0r + lo8);
                a0hi = *(const h16x8*)(h0r + lo8 + 512);
            }
            if (ia) {
                const int tn = t + 1;
                axn = *(const h16x8*)&XL[((tn >> 5) & 1) * (32 * 512) + (tn & 31) * 512 + lo8];
            }
            if (sa) {
                #pragma unroll
                for (int g = 0; g < 4; ++g) {
                    z[g] = MFMA16(a0lo, Bf[g][1], zc[g]);
                    z[g] = MFMA16(a0hi, Bf[g][2], z[g]);
                }
            }
            if ((t & 31) == 16 && (t >> 5) < 15) stage_x((t >> 5) + 1);
            if (sa) ew(z[0], z[1], z[2], z[3], h0w);
            if (ia) {
                #pragma unroll
                for (int g = 0; g < 4; ++g)
                    zc[g] = MFMA16(axn, Bf[g][0], zb[g]);
            }
        } else if (wl == 1) {    // ---- L1: self for step t-2, input-prefetch t-1 ----
            const bool sa = !EDGE || (t >= 2 && t < TT + 2);
            const bool ia = !EDGE || (t >= 1 && t < TT + 1);
            f32x4 z[4];
            h16x8 a1lo, a1hi, a0lo, a0hi;
            if (sa) {
                a1lo = *(const h16x8*)(h1r + lo8);
                a1hi = *(const h16x8*)(h1r + lo8 + 512);
            }
            if (ia) {
                a0lo = *(const h16x8*)(h0r + lo8);
                a0hi = *(const h16x8*)(h0r + lo8 + 512);
            }
            if (sa) {
                #pragma unroll
                for (int g = 0; g < 4; ++g) {
                    z[g] = MFMA16(a1lo, Bf[g][2], zc[g]);
                    z[g] = MFMA16(a1hi, Bf[g][3], z[g]);
                }
            }
            if (sa) ew(z[0], z[1], z[2], z[3], h1w);
            if (ia) {
                #pragma unroll
                for (int g = 0; g < 4; ++g) {
                    f32x4 zn = MFMA16(a0lo, Bf[g][0], zb[g]);
                    zc[g] = MFMA16(a0hi, Bf[g][1], zn);
                }
            }
        } else {                 // ------ L2: self for step t-4, input-prefetch t-3 ------
            const bool sa = !EDGE || (t >= 4);
            const bool ia = !EDGE || (t >= 3 && t < TT + 3);
            f32x4 z[4];
            h16x8 a2lo, a2hi, a1lo, a1hi;
            if (sa) {
                a2lo = *(const h16x8*)(h2r + lo8);
                a2hi = *(const h16x8*)(h2r + lo8 + 512);
            }
            if (ia) {
                a1lo = *(const h16x8*)(h1r + lo8);
                a1hi = *(const h16x8*)(h1r + lo8 + 512);
            }
            if (sa) {
                #pragma unroll
                for (int g = 0; g < 4; ++g) {
                    z[g] = MFMA16(a2lo, Bf[g][2], zc[g]);
                    z[g] = MFMA16(a2hi, Bf[g][3], z[g]);
                }
            }
            if (sa) ew(z[0], z[1], z[2], z[3], h2w);
            if (ia) {
                #pragma unroll
                for (int g = 0; g < 4; ++g) {
                    f32x4 zn = MFMA16(a1lo, Bf[g][0], zb[g]);
                    zc[g] = MFMA16(a1hi, Bf[g][1], zn);
                }
            }
        }

        __syncthreads();
    };

    #pragma unroll 1
    for (int t = 0; t < 4; ++t) tick(t, TrueC{});
    #pragma unroll 1
    for (int t = 4; t < TT - 1; ++t) tick(t, FalseC{});     // branch-free steady state
    #pragma unroll 1
    for (int t = TT - 1; t < TT + 4; ++t) tick(t, TrueC{});

    // ------------- FC epilogue: h2(step 511) is in buffer (TT+1)&1 = 1 -----------
    if (tid < 16) {
        const int ms = tid >> 2, o = tid & 3;
        const h16* h2 = HT + 2 * 2048 + 1024;
        float acc = bfc[o];
        #pragma unroll 1
        for (int uu = 0; uu < 64; ++uu)
            acc += (float)h2[(uu >> 3) * 128 + (4 * ms) * 8 + (uu & 7)] * wfc[o * 64 + uu];
        out[(b4 + ms) * 4 + o] = acc;
    }
}

extern "C" void kernel_launch(void* const* d_in, const int* in_sizes, int n_in,
                              void* d_out, int out_size, void* d_ws, size_t ws_size,
                              hipStream_t stream) {
    const float* x    = (const float*)d_in[0];
    const float* wih0 = (const float*)d_in[1];
    const float* whh0 = (const float*)d_in[2];
    const float* bih0 = (const float*)d_in[3];
    const float* bhh0 = (const float*)d_in[4];
    const float* wih1 = (const float*)d_in[5];
    const float* whh1 = (const float*)d_in[6];
    const float* bih1 = (const float*)d_in[7];
    const float* bhh1 = (const float*)d_in[8];
    const float* wih2 = (const float*)d_in[9];
    const float* whh2 = (const float*)d_in[10];
    const float* bih2 = (const float*)d_in[11];
    const float* bhh2 = (const float*)d_in[12];
    const float* wfc  = (const float*)d_in[13];
    const float* bfc  = (const float*)d_in[14];
    float* out = (float*)d_out;

    lstm_mfma<<<dim3(NBLK), dim3(NTH), 0, stream>>>(
        x, wih0, whh0, bih0, bhh0, wih1, whh1, bih1, bhh1,
        wih2, whh2, bih2, bhh2, wfc, bfc, out);
}

// Round 12
// 351.820 us; speedup vs baseline: 3960.1056x; 1.0815x over previous
//
#include <hip/hip_runtime.h>

// LSTM_61203283968689 — R18: TIME-BATCHED INPUT PROJECTIONS (M-row packing).
// R17 validated the additive model: tick = MFMA(750) + VALU(634) + barrier.
// MFMA M-efficiency is 25% (4 real sample rows of 16). The input-half GEMMs
// (W_ih·x for L0, W_ih·h_below for L1/L2) are batchable over time: pack
// (sample bl, step j) at C/A row 4*bl+j -> one MFMA/gate/K-half serves 4 steps.
// Diagonal deepened: L0 lag 0, L1 lag 4, L2 lag 8 (520 ticks, groups of 4).
// Group G: batch at tick 4G (L0: x steps 4G..4G+3; L1: h0 steps 4G-4..4G-1;
// L2: h1 steps 4G-8..4G-5), then 4 self-ticks consume zB[g][j] as C-in reg0.
// h rings depth 8 (slot = step&7; all writer/reader slots distinct mod 8,
// barrier-separated - verified). MFMA/SIMD/tick 44 -> 29 (750 -> 563 cyc).
// Accumulation order per gate unchanged (bias, ih-lo, ih-hi, hh-lo, hh-hi)
// -> bit-identical output (absmax must stay 0.0009765625).
// R17's 7-trans ew + pre-scaled weights kept. LDS: XL 64K + HR 48K = 112 KiB
// -> 1 block/CU (PAD dropped). Steady groups 2..127 branch-free.

#define TT   512
#define NTH  768
#define NBLK 256

typedef _Float16 h16;
typedef __attribute__((ext_vector_type(8))) _Float16 h16x8;
typedef __attribute__((ext_vector_type(4))) float f32x4;

#define MFMA16(a, b, c) __builtin_amdgcn_mfma_f32_16x16x32_f16((a), (b), (c), 0, 0, 0)

#define NLOG2E  -1.4426950408889634f   // -log2(e)
#define N2LOG2E -2.8853900817779268f   // -2*log2(e)

// B-fragment: 8 consecutive k of row `ro` from row-major W[.,ld], f32 -> f16,
// pre-scaled so exp2(z') = exp(-z) (i,f,o) / exp(-2z) (g).
__device__ __forceinline__ h16x8 loadB(const float* __restrict__ W, int ld, int ro,
                                       int k0, int kmax, float scale) {
    h16x8 r;
    #pragma unroll
    for (int i = 0; i < 8; ++i) {
        const int k = k0 + i;
        r[i] = (h16)((k < kmax) ? scale * W[(size_t)ro * ld + k] : 0.f);
    }
    return r;
}

struct TrueC  { static constexpr bool value = true;  };
struct FalseC { static constexpr bool value = false; };

__global__ __attribute__((amdgpu_flat_work_group_size(NTH, NTH), amdgpu_waves_per_eu(3)))
void lstm_mfma(
    const float* __restrict__ x,
    const float* __restrict__ wih0, const float* __restrict__ whh0,
    const float* __restrict__ bih0, const float* __restrict__ bhh0,
    const float* __restrict__ wih1, const float* __restrict__ whh1,
    const float* __restrict__ bih1, const float* __restrict__ bhh1,
    const float* __restrict__ wih2, const float* __restrict__ whh2,
    const float* __restrict__ bih2, const float* __restrict__ bhh2,
    const float* __restrict__ wfc, const float* __restrict__ bfc,
    float* __restrict__ out)
{
    const int tid  = threadIdx.x;
    const int w    = tid >> 6;        // wave 0..11
    const int wl   = w >> 2;          // layer 0..2
    const int wg   = w & 3;           // gate-tile group: units [16wg, 16wg+16)
    const int lane = tid & 63;
    const int nloc = lane & 15;       // unit-local index / B-frag col
    const int kg   = lane >> 4;       // k-group; also sample (C-row 4*kg, reg 0)
    const int b4   = blockIdx.x * 4;
    const int u    = wg * 16 + nloc;  // this lane's hidden unit

    // LDS: XL 64 KiB + HR 48 KiB = 112 KiB -> 1 block/CU
    __shared__ alignas(16) h16 XL[2 * 32 * 512];   // x, 2 chunks x 32 t x frag-tile(512)
    __shared__ alignas(16) h16 HR[3 * 8 * 1024];   // h rings: [layer][step&7][1024]

    // ---------------- B fragments (R17 pre-scaled) ----------------
    h16x8 Bf[4][4];
    float bias[4];
    #pragma unroll
    for (int g = 0; g < 4; ++g) {
        const int ro = g * 64 + u;
        const float sc = (g == 2) ? N2LOG2E : NLOG2E;
        if (wl == 0) {
            Bf[g][0] = loadB(wih0, 22, ro, kg * 8,      22, sc);
            Bf[g][1] = loadB(whh0, 64, ro, kg * 8,      64, sc);
            Bf[g][2] = loadB(whh0, 64, ro, 32 + kg * 8, 64, sc);
            Bf[g][3] = Bf[g][2];
            bias[g]  = sc * (bih0[ro] + bhh0[ro]);
        } else if (wl == 1) {
            Bf[g][0] = loadB(wih1, 64, ro, kg * 8,      64, sc);
            Bf[g][1] = loadB(wih1, 64, ro, 32 + kg * 8, 64, sc);
            Bf[g][2] = loadB(whh1, 64, ro, kg * 8,      64, sc);
            Bf[g][3] = loadB(whh1, 64, ro, 32 + kg * 8, 64, sc);
            bias[g]  = sc * (bih1[ro] + bhh1[ro]);
        } else {
            Bf[g][0] = loadB(wih2, 64, ro, kg * 8,      64, sc);
            Bf[g][1] = loadB(wih2, 64, ro, 32 + kg * 8, 64, sc);
            Bf[g][2] = loadB(whh2, 64, ro, kg * 8,      64, sc);
            Bf[g][3] = loadB(whh2, 64, ro, 32 + kg * 8, 64, sc);
            bias[g]  = sc * (bih2[ro] + bhh2[ro]);
        }
    }

    // ---------------- zero LDS (x k-pad + tile pad rows + h(-1) slots) --------
    {
        int* xz = (int*)XL;
        for (int i = tid; i < 2 * 32 * 256; i += NTH) xz[i] = 0;
        int* hz = (int*)HR;
        for (int i = tid; i < 3 * 8 * 512; i += NTH) hz[i] = 0;
    }
    __syncthreads();

    // ---------------- x staging (unchanged layout) ----------------
    auto stage_x = [&](int chunk) {
        if (tid < 4 * 22) {
            const int bl = tid / 22, ii = tid - bl * 22;
            const float* src = x + (size_t)(b4 + bl) * (22 * 512) + (size_t)ii * 512
                                 + chunk * 32;
            h16* dst = &XL[(chunk & 1) * (32 * 512) + (ii >> 3) * 128 + (4 * bl) * 8 + (ii & 7)];
            #pragma unroll
            for (int q = 0; q < 8; ++q) {
                const float4 v = ((const float4*)src)[q];
                dst[(q * 4 + 0) * 512] = (h16)v.x;
                dst[(q * 4 + 1) * 512] = (h16)v.y;
                dst[(q * 4 + 2) * 512] = (h16)v.z;
                dst[(q * 4 + 3) * 512] = (h16)v.w;
            }
        }
    };
    stage_x(0);

    // ---------------- per-lane constants ----------------
    const int lo8  = lane * 8;                           // self A-frag offset
    const int hoff = (u >> 3) * 128 + kg * 32 + (u & 7); // h-write: row 4*kg, unit u
    const int bj   = lane & 3;                           // batch: step offset (row&3)
    const int boff = (lane >> 4) * 128 + ((lane & 15) >> 2) * 32;  // batch in-tile off

    float cst = 0.f;

    // R17 ew: 7 trans (5 exp2 + 2 rcp), fused denominators
    auto ew = [&](const f32x4& zi, const f32x4& zf, const f32x4& zg, const f32x4& zo,
                  h16* hb) {
        const float ei = __builtin_amdgcn_exp2f(zi[0]);
        const float ef = __builtin_amdgcn_exp2f(zf[0]);
        const float eg = __builtin_amdgcn_exp2f(zg[0]);
        const float eo = __builtin_amdgcn_exp2f(zo[0]);
        const float pig = (1.f + ei) * (1.f + eg);
        const float pf  = 1.f + ef;
        const float n   = cst * pig + (1.f - eg) * pf;
        const float c   = n * __builtin_amdgcn_rcpf(pf * pig);
        cst = c;
        const float ea  = fminf(c * N2LOG2E, 126.f);
        const float ec  = __builtin_amdgcn_exp2f(ea);
        const float h   = (1.f - ec)
                        * __builtin_amdgcn_rcpf((1.f + ec) * (1.f + eo));
        hb[hoff] = (h16)h;
    };

    __syncthreads();

    h16* const HR0 = HR;
    h16* const HR1 = HR + 8192;
    h16* const HR2 = HR + 16384;

    // ======================= 4-tick group =======================
    // L0: batch x steps 4G..4G+3; self step 4G+j at tick j.
    // L1: batch h0 steps 4G-4..4G-1; self step 4G-4+j.
    // L2: batch h1 steps 4G-8..4G-5; self step 4G-8+j.
    auto group = [&](int G, auto edgec) {
        constexpr bool EDGE = decltype(edgec)::value;
        f32x4 zB[4];

        if (wl == 0) {
            const bool act = !EDGE || (G <= 127);
            if (act) {
                const int t0 = 4 * G;
                const h16x8 axB = *(const h16x8*)
                    &XL[((t0 >> 5) & 1) * 16384 + ((t0 & 31) + bj) * 512 + boff];
                #pragma unroll
                for (int g = 0; g < 4; ++g) {
                    const f32x4 zb4 = {bias[g], bias[g], bias[g], bias[g]};
                    zB[g] = MFMA16(axB, Bf[g][0], zb4);
                }
            }
            #pragma unroll
            for (int j = 0; j < 4; ++j) {
                if (act) {
                    const int t = 4 * G + j;
                    const h16* sr = HR0 + ((t - 1) & 7) * 1024;
                    h16*       sw = HR0 + (t & 7) * 1024;
                    const h16x8 alo = *(const h16x8*)(sr + lo8);
                    const h16x8 ahi = *(const h16x8*)(sr + lo8 + 512);
                    f32x4 z[4];
                    #pragma unroll
                    for (int g = 0; g < 4; ++g) {
                        const f32x4 cin = {zB[g][j], 0.f, 0.f, 0.f};
                        z[g] = MFMA16(alo, Bf[g][1], cin);
                        z[g] = MFMA16(ahi, Bf[g][2], z[g]);
                    }
                    if (j == 0 && (G & 7) == 4 && (G >> 3) < 15) stage_x((G >> 3) + 1);
                    ew(z[0], z[1], z[2], z[3], sw);
                }
                __syncthreads();
            }
        } else if (wl == 1) {
            const bool act = !EDGE || (G >= 1 && G <= 128);
            if (act) {
                const int sB = 4 * G - 4;
                const h16* hb = HR0 + ((sB + bj) & 7) * 1024 + boff;
                const h16x8 blo = *(const h16x8*)hb;
                const h16x8 bhi = *(const h16x8*)(hb + 512);
                #pragma unroll
                for (int g = 0; g < 4; ++g) {
                    const f32x4 zb4 = {bias[g], bias[g], bias[g], bias[g]};
                    f32x4 zt = MFMA16(blo, Bf[g][0], zb4);
                    zB[g] = MFMA16(bhi, Bf[g][1], zt);
                }
            }
            #pragma unroll
            for (int j = 0; j < 4; ++j) {
                if (act) {
                    const int s = 4 * G - 4 + j;
                    const h16* sr = HR1 + ((s - 1) & 7) * 1024;
                    h16*       sw = HR1 + (s & 7) * 1024;
                    const h16x8 alo = *(const h16x8*)(sr + lo8);
                    const h16x8 ahi = *(const h16x8*)(sr + lo8 + 512);
                    f32x4 z[4];
                    #pragma unroll
                    for (int g = 0; g < 4; ++g) {
                        const f32x4 cin = {zB[g][j], 0.f, 0.f, 0.f};
                        z[g] = MFMA16(alo, Bf[g][2], cin);
                        z[g] = MFMA16(ahi, Bf[g][3], z[g]);
                    }
                    ew(z[0], z[1], z[2], z[3], sw);
                }
                __syncthreads();
            }
        } else {
            const bool act = !EDGE || (G >= 2);
            if (act) {
                const int sB = 4 * G - 8;
                const h16* hb = HR1 + ((sB + bj) & 7) * 1024 + boff;
                const h16x8 blo = *(const h16x8*)hb;
                const h16x8 bhi = *(const h16x8*)(hb + 512);
                #pragma unroll
                for (int g = 0; g < 4; ++g) {
                    const f32x4 zb4 = {bias[g], bias[g], bias[g], bias[g]};
                    f32x4 zt = MFMA16(blo, Bf[g][0], zb4);
                    zB[g] = MFMA16(bhi, Bf[g][1], zt);
                }
            }
            #pragma unroll
            for (int j = 0; j < 4; ++j) {
                if (act) {
                    const int s = 4 * G - 8 + j;
                    const h16* sr = HR2 + ((s - 1) & 7) * 1024;
                    h16*       sw = HR2 + (s & 7) * 1024;
                    const h16x8 alo = *(const h16x8*)(sr + lo8);
                    const h16x8 ahi = *(const h16x8*)(sr + lo8 + 512);
                    f32x4 z[4];
                    #pragma unroll
                    for (int g = 0; g < 4; ++g) {
                        const f32x4 cin = {zB[g][j], 0.f, 0.f, 0.f};
                        z[g] = MFMA16(alo, Bf[g][2], cin);
                        z[g] = MFMA16(ahi, Bf[g][3], z[g]);
                    }
                    ew(z[0], z[1], z[2], z[3], sw);
                }
                __syncthreads();
            }
        }
    };

    group(0, TrueC{});
    group(1, TrueC{});
    #pragma unroll 1
    for (int G = 2; G < 128; ++G) group(G, FalseC{});   // branch-free steady state
    group(128, TrueC{});
    group(129, TrueC{});

    // ------------- FC epilogue: h2(step 511) in ring slot 511&7 = 7 -----------
    if (tid < 16) {
        const int ms = tid >> 2, o = tid & 3;
        const h16* h2 = HR2 + 7 * 1024;
        float acc = bfc[o];
        #pragma unroll 1
        for (int uu = 0; uu < 64; ++uu)
            acc += (float)h2[(uu >> 3) * 128 + (4 * ms) * 8 + (uu & 7)] * wfc[o * 64 + uu];
        out[(b4 + ms) * 4 + o] = acc;
    }
}

extern "C" void kernel_launch(void* const* d_in, const int* in_sizes, int n_in,
                              void* d_out, int out_size, void* d_ws, size_t ws_size,
                              hipStream_t stream) {
    const float* x    = (const float*)d_in[0];
    const float* wih0 = (const float*)d_in[1];
    const float* whh0 = (const float*)d_in[2];
    const float* bih0 = (const float*)d_in[3];
    const float* bhh0 = (const float*)d_in[4];
    const float* wih1 = (const float*)d_in[5];
    const float* whh1 = (const float*)d_in[6];
    const float* bih1 = (const float*)d_in[7];
    const float* bhh1 = (const float*)d_in[8];
    const float* wih2 = (const float*)d_in[9];
    const float* whh2 = (const float*)d_in[10];
    const float* bih2 = (const float*)d_in[11];
    const float* bhh2 = (const float*)d_in[12];
    const float* wfc  = (const float*)d_in[13];
    const float* bfc  = (const float*)d_in[14];
    float* out = (float*)d_out;

    lstm_mfma<<<dim3(NBLK), dim3(NTH), 0, stream>>>(
        x, wih0, whh0, bih0, bhh0, wih1, whh1, bih1, bhh1,
        wih2, whh2, bih2, bhh2, wfc, bfc, out);
}

// Round 13
// 349.071 us; speedup vs baseline: 3991.2931x; 1.0079x over previous
//
#include <hip/hip_runtime.h>

// LSTM_61203283968689 — R19: R18 (288 µs) + BANK-CONFLICT SWIZZLE on batch reads.
// R18's batch ds_read_b128 (boff = {0,64,128,192}B steps; slab strides 1024B/XL,
// 2048B/HR, both ==0 mod 128B) put all 64 lanes on 8 of 32 banks -> 4x
// serialization (SQ_LDS_BANK_CONFLICT 3.9M -> 11.8M, ~120 cy/tick).
// Fix: +16B per slab -> XL t-slab stride 512->520 h16, HR slot stride
// 1024->1032 h16. Batch lanes hit slabs +bj (bj=lane&3) -> bank sets rotate
// 4*bj -> 64 lanes cover all 32 banks evenly (8-cy floor). Self reads/writes
// use one slot per instr (uniform base shift, pattern unchanged). 16B
// alignment kept (1040, 2064 both %16==0). Math untouched -> bit-identical
// (absmax must stay 0.0009765625). LDS 113.4 KiB -> 1 block/CU.
// Structure from R18: time-batched input projections (M-packed 4 steps),
// L0 lag 0 / L1 lag 4 / L2 lag 8, rings depth 8, R17 7-trans ew + pre-scaled
// weights. Budget: tick 1328 = MFMA 487 + VALU 653 + ~190 (conflict+barrier).

#define TT   512
#define NTH  768
#define NBLK 256

#define XSLB 520                  // x t-slab stride (h16): 512 data + 8 pad
#define XCH  (32 * XSLB)          // 16640 h16 per chunk
#define HSLB 1032                 // h ring-slot stride (h16): 1024 data + 8 pad
#define HLAY (8 * HSLB)           // 8256 h16 per layer ring

typedef _Float16 h16;
typedef __attribute__((ext_vector_type(8))) _Float16 h16x8;
typedef __attribute__((ext_vector_type(4))) float f32x4;

#define MFMA16(a, b, c) __builtin_amdgcn_mfma_f32_16x16x32_f16((a), (b), (c), 0, 0, 0)

#define NLOG2E  -1.4426950408889634f   // -log2(e)
#define N2LOG2E -2.8853900817779268f   // -2*log2(e)

// B-fragment: 8 consecutive k of row `ro` from row-major W[.,ld], f32 -> f16,
// pre-scaled so exp2(z') = exp(-z) (i,f,o) / exp(-2z) (g).
__device__ __forceinline__ h16x8 loadB(const float* __restrict__ W, int ld, int ro,
                                       int k0, int kmax, float scale) {
    h16x8 r;
    #pragma unroll
    for (int i = 0; i < 8; ++i) {
        const int k = k0 + i;
        r[i] = (h16)((k < kmax) ? scale * W[(size_t)ro * ld + k] : 0.f);
    }
    return r;
}

struct TrueC  { static constexpr bool value = true;  };
struct FalseC { static constexpr bool value = false; };

__global__ __attribute__((amdgpu_flat_work_group_size(NTH, NTH), amdgpu_waves_per_eu(3)))
void lstm_mfma(
    const float* __restrict__ x,
    const float* __restrict__ wih0, const float* __restrict__ whh0,
    const float* __restrict__ bih0, const float* __restrict__ bhh0,
    const float* __restrict__ wih1, const float* __restrict__ whh1,
    const float* __restrict__ bih1, const float* __restrict__ bhh1,
    const float* __restrict__ wih2, const float* __restrict__ whh2,
    const float* __restrict__ bih2, const float* __restrict__ bhh2,
    const float* __restrict__ wfc, const float* __restrict__ bfc,
    float* __restrict__ out)
{
    const int tid  = threadIdx.x;
    const int w    = tid >> 6;        // wave 0..11
    const int wl   = w >> 2;          // layer 0..2
    const int wg   = w & 3;           // gate-tile group: units [16wg, 16wg+16)
    const int lane = tid & 63;
    const int nloc = lane & 15;       // unit-local index / B-frag col
    const int kg   = lane >> 4;       // k-group; also sample (C-row 4*kg, reg 0)
    const int b4   = blockIdx.x * 4;
    const int u    = wg * 16 + nloc;  // this lane's hidden unit

    // LDS: XL 65 KiB + HR 48.4 KiB = 113.4 KiB -> 1 block/CU
    __shared__ alignas(16) h16 XL[2 * XCH];    // x: [2 chunks][32 t-slabs(520)]
    __shared__ alignas(16) h16 HR[3 * HLAY];   // h rings: [layer][8 slots(1032)]

    // ---------------- B fragments (R17 pre-scaled) ----------------
    h16x8 Bf[4][4];
    float bias[4];
    #pragma unroll
    for (int g = 0; g < 4; ++g) {
        const int ro = g * 64 + u;
        const float sc = (g == 2) ? N2LOG2E : NLOG2E;
        if (wl == 0) {
            Bf[g][0] = loadB(wih0, 22, ro, kg * 8,      22, sc);
            Bf[g][1] = loadB(whh0, 64, ro, kg * 8,      64, sc);
            Bf[g][2] = loadB(whh0, 64, ro, 32 + kg * 8, 64, sc);
            Bf[g][3] = Bf[g][2];
            bias[g]  = sc * (bih0[ro] + bhh0[ro]);
        } else if (wl == 1) {
            Bf[g][0] = loadB(wih1, 64, ro, kg * 8,      64, sc);
            Bf[g][1] = loadB(wih1, 64, ro, 32 + kg * 8, 64, sc);
            Bf[g][2] = loadB(whh1, 64, ro, kg * 8,      64, sc);
            Bf[g][3] = loadB(whh1, 64, ro, 32 + kg * 8, 64, sc);
            bias[g]  = sc * (bih1[ro] + bhh1[ro]);
        } else {
            Bf[g][0] = loadB(wih2, 64, ro, kg * 8,      64, sc);
            Bf[g][1] = loadB(wih2, 64, ro, 32 + kg * 8, 64, sc);
            Bf[g][2] = loadB(whh2, 64, ro, kg * 8,      64, sc);
            Bf[g][3] = loadB(whh2, 64, ro, 32 + kg * 8, 64, sc);
            bias[g]  = sc * (bih2[ro] + bhh2[ro]);
        }
    }

    // ---------------- zero LDS (x k-pad + slab pads + h(-1) slots) --------
    {
        int* xz = (int*)XL;
        for (int i = tid; i < XCH; i += NTH) xz[i] = 0;            // 2*XCH h16
        int* hz = (int*)HR;
        for (int i = tid; i < (3 * HLAY) / 2; i += NTH) hz[i] = 0;
    }
    __syncthreads();

    // ---------------- x staging (slab stride XSLB) ----------------
    auto stage_x = [&](int chunk) {
        if (tid < 4 * 22) {
            const int bl = tid / 22, ii = tid - bl * 22;
            const float* src = x + (size_t)(b4 + bl) * (22 * 512) + (size_t)ii * 512
                                 + chunk * 32;
            h16* dst = &XL[(chunk & 1) * XCH + (ii >> 3) * 128 + (4 * bl) * 8 + (ii & 7)];
            #pragma unroll
            for (int q = 0; q < 8; ++q) {
                const float4 v = ((const float4*)src)[q];
                dst[(q * 4 + 0) * XSLB] = (h16)v.x;
                dst[(q * 4 + 1) * XSLB] = (h16)v.y;
                dst[(q * 4 + 2) * XSLB] = (h16)v.z;
                dst[(q * 4 + 3) * XSLB] = (h16)v.w;
            }
        }
    };
    stage_x(0);

    // ---------------- per-lane constants ----------------
    const int lo8  = lane * 8;                           // self A-frag offset
    const int hoff = (u >> 3) * 128 + kg * 32 + (u & 7); // h-write: row 4*kg, unit u
    const int bj   = lane & 3;                           // batch: step offset (row&3)
    const int boff = (lane >> 4) * 128 + ((lane & 15) >> 2) * 32;  // batch in-tile off

    float cst = 0.f;

    // R17 ew: 7 trans (5 exp2 + 2 rcp), fused denominators
    auto ew = [&](const f32x4& zi, const f32x4& zf, const f32x4& zg, const f32x4& zo,
                  h16* hb) {
        const float ei = __builtin_amdgcn_exp2f(zi[0]);
        const float ef = __builtin_amdgcn_exp2f(zf[0]);
        const float eg = __builtin_amdgcn_exp2f(zg[0]);
        const float eo = __builtin_amdgcn_exp2f(zo[0]);
        const float pig = (1.f + ei) * (1.f + eg);
        const float pf  = 1.f + ef;
        const float n   = cst * pig + (1.f - eg) * pf;
        const float c   = n * __builtin_amdgcn_rcpf(pf * pig);
        cst = c;
        const float ea  = fminf(c * N2LOG2E, 126.f);
        const float ec  = __builtin_amdgcn_exp2f(ea);
        const float h   = (1.f - ec)
                        * __builtin_amdgcn_rcpf((1.f + ec) * (1.f + eo));
        hb[hoff] = (h16)h;
    };

    __syncthreads();

    h16* const HR0 = HR;
    h16* const HR1 = HR + HLAY;
    h16* const HR2 = HR + 2 * HLAY;

    // ======================= 4-tick group =======================
    // L0: batch x steps 4G..4G+3; self step 4G+j at tick j.
    // L1: batch h0 steps 4G-4..4G-1; self step 4G-4+j.
    // L2: batch h1 steps 4G-8..4G-5; self step 4G-8+j.
    auto group = [&](int G, auto edgec) {
        constexpr bool EDGE = decltype(edgec)::value;
        f32x4 zB[4];

        if (wl == 0) {
            const bool act = !EDGE || (G <= 127);
            if (act) {
                const int t0 = 4 * G;
                const h16x8 axB = *(const h16x8*)
                    &XL[((t0 >> 5) & 1) * XCH + ((t0 & 31) + bj) * XSLB + boff];
                #pragma unroll
                for (int g = 0; g < 4; ++g) {
                    const f32x4 zb4 = {bias[g], bias[g], bias[g], bias[g]};
                    zB[g] = MFMA16(axB, Bf[g][0], zb4);
                }
            }
            #pragma unroll
            for (int j = 0; j < 4; ++j) {
                if (act) {
                    const int t = 4 * G + j;
                    const h16* sr = HR0 + ((t - 1) & 7) * HSLB;
                    h16*       sw = HR0 + (t & 7) * HSLB;
                    const h16x8 alo = *(const h16x8*)(sr + lo8);
                    const h16x8 ahi = *(const h16x8*)(sr + lo8 + 512);
                    f32x4 z[4];
                    #pragma unroll
                    for (int g = 0; g < 4; ++g) {
                        const f32x4 cin = {zB[g][j], 0.f, 0.f, 0.f};
                        z[g] = MFMA16(alo, Bf[g][1], cin);
                        z[g] = MFMA16(ahi, Bf[g][2], z[g]);
                    }
                    if (j == 0 && (G & 7) == 4 && (G >> 3) < 15) stage_x((G >> 3) + 1);
                    ew(z[0], z[1], z[2], z[3], sw);
                }
                __syncthreads();
            }
        } else if (wl == 1) {
            const bool act = !EDGE || (G >= 1 && G <= 128);
            if (act) {
                const int sB = 4 * G - 4;
                const h16* hb = HR0 + ((sB + bj) & 7) * HSLB + boff;
                const h16x8 blo = *(const h16x8*)hb;
                const h16x8 bhi = *(const h16x8*)(hb + 512);
                #pragma unroll
                for (int g = 0; g < 4; ++g) {
                    const f32x4 zb4 = {bias[g], bias[g], bias[g], bias[g]};
                    f32x4 zt = MFMA16(blo, Bf[g][0], zb4);
                    zB[g] = MFMA16(bhi, Bf[g][1], zt);
                }
            }
            #pragma unroll
            for (int j = 0; j < 4; ++j) {
                if (act) {
                    const int s = 4 * G - 4 + j;
                    const h16* sr = HR1 + ((s - 1) & 7) * HSLB;
                    h16*       sw = HR1 + (s & 7) * HSLB;
                    const h16x8 alo = *(const h16x8*)(sr + lo8);
                    const h16x8 ahi = *(const h16x8*)(sr + lo8 + 512);
                    f32x4 z[4];
                    #pragma unroll
                    for (int g = 0; g < 4; ++g) {
                        const f32x4 cin = {zB[g][j], 0.f, 0.f, 0.f};
                        z[g] = MFMA16(alo, Bf[g][2], cin);
                        z[g] = MFMA16(ahi, Bf[g][3], z[g]);
                    }
                    ew(z[0], z[1], z[2], z[3], sw);
                }
                __syncthreads();
            }
        } else {
            const bool act = !EDGE || (G >= 2);
            if (act) {
                const int sB = 4 * G - 8;
                const h16* hb = HR1 + ((sB + bj) & 7) * HSLB + boff;
                const h16x8 blo = *(const h16x8*)hb;
                const h16x8 bhi = *(const h16x8*)(hb + 512);
                #pragma unroll
                for (int g = 0; g < 4; ++g) {
                    const f32x4 zb4 = {bias[g], bias[g], bias[g], bias[g]};
                    f32x4 zt = MFMA16(blo, Bf[g][0], zb4);
                    zB[g] = MFMA16(bhi, Bf[g][1], zt);
                }
            }
            #pragma unroll
            for (int j = 0; j < 4; ++j) {
                if (act) {
                    const int s = 4 * G - 8 + j;
                    const h16* sr = HR2 + ((s - 1) & 7) * HSLB;
                    h16*       sw = HR2 + (s & 7) * HSLB;
                    const h16x8 alo = *(const h16x8*)(sr + lo8);
                    const h16x8 ahi = *(const h16x8*)(sr + lo8 + 512);
                    f32x4 z[4];
                    #pragma unroll
                    for (int g = 0; g < 4; ++g) {
                        const f32x4 cin = {zB[g][j], 0.f, 0.f, 0.f};
                        z[g] = MFMA16(alo, Bf[g][2], cin);
                        z[g] = MFMA16(ahi, Bf[g][3], z[g]);
                    }
                    ew(z[0], z[1], z[2], z[3], sw);
                }
                __syncthreads();
            }
        }
    };

    group(0, TrueC{});
    group(1, TrueC{});
    #pragma unroll 1
    for (int G = 2; G < 128; ++G) group(G, FalseC{});   // branch-free steady state
    group(128, TrueC{});
    group(129, TrueC{});

    // ------------- FC epilogue: h2(step 511) in ring slot 511&7 = 7 -----------
    if (tid < 16) {
        const int ms = tid >> 2, o = tid & 3;
        const h16* h2 = HR + 2 * HLAY + 7 * HSLB;
        float acc = bfc[o];
        #pragma unroll 1
        for (int uu = 0; uu < 64; ++uu)
            acc += (float)h2[(uu >> 3) * 128 + (4 * ms) * 8 + (uu & 7)] * wfc[o * 64 + uu];
        out[(b4 + ms) * 4 + o] = acc;
    }
}

extern "C" void kernel_launch(void* const* d_in, const int* in_sizes, int n_in,
                              void* d_out, int out_size, void* d_ws, size_t ws_size,
                              hipStream_t stream) {
    const float* x    = (const float*)d_in[0];
    const float* wih0 = (const float*)d_in[1];
    const float* whh0 = (const float*)d_in[2];
    const float* bih0 = (const float*)d_in[3];
    const float* bhh0 = (const float*)d_in[4];
    const float* wih1 = (const float*)d_in[5];
    const float* whh1 = (const float*)d_in[6];
    const float* bih1 = (const float*)d_in[7];
    const float* bhh1 = (const float*)d_in[8];
    const float* wih2 = (const float*)d_in[9];
    const float* whh2 = (const float*)d_in[10];
    const float* bih2 = (const float*)d_in[11];
    const float* bhh2 = (const float*)d_in[12];
    const float* wfc  = (const float*)d_in[13];
    const float* bfc  = (const float*)d_in[14];
    float* out = (float*)d_out;

    lstm_mfma<<<dim3(NBLK), dim3(NTH), 0, stream>>>(
        x, wih0, whh0, bih0, bhh0, wih1, whh1, bih1, bhh1,
        wih2, whh2, bih2, bhh2, wfc, bfc, out);
}

// Round 14
// 341.207 us; speedup vs baseline: 4083.2797x; 1.0230x over previous
//
#include <hip/hip_runtime.h>

// LSTM_61203283968689 — R20: R19 (287 µs) + COMPILE-TIME LDS ADDRESSING.
// R19 budget: tick 1327 = MFMA 484 (at GEMM floor: 32 N*K tiles/layer-tick)
// + VALU 656 + ~190 latency/barrier. VALU fit: ew ~115 cy/wave + ~95 cy/wave
// UNEXPLAINED -> suspects: per-tick ring-slot address chains ((t±1)&7*HSLB),
// rebuilt zb4/cin tuples, batch-offset recomputation.
// R20: ring slots have period 2 in G (4G mod 8 in {0,4}) -> steady group
// specialized on PAR=G&1 folds ALL slot indices to constants (verified for
// L0/L1/L2 reads+writes+batch bases; no &7 wrap inside a quad). ds ops become
// base-reg + immediate. Per-lane batch offsets (bj*HSLB+boff, bj*XSLB+boff)
// and zb4 broadcast tuples hoisted to persistent registers.
// Math/order/layout untouched -> bit-identical (absmax must stay 0.0009765625).
// Edge groups (4/130) keep the runtime-slot path. R19's swizzle kept (free).
// If this is null, the kernel is at its issue-sum floor -> ROOFLINE.

#define TT   512
#define NTH  768
#define NBLK 256

#define XSLB 520                  // x t-slab stride (h16): 512 data + 8 pad
#define XCH  (32 * XSLB)          // 16640 h16 per chunk
#define HSLB 1032                 // h ring-slot stride (h16): 1024 data + 8 pad
#define HLAY (8 * HSLB)           // 8256 h16 per layer ring

typedef _Float16 h16;
typedef __attribute__((ext_vector_type(8))) _Float16 h16x8;
typedef __attribute__((ext_vector_type(4))) float f32x4;

#define MFMA16(a, b, c) __builtin_amdgcn_mfma_f32_16x16x32_f16((a), (b), (c), 0, 0, 0)

#define NLOG2E  -1.4426950408889634f   // -log2(e)
#define N2LOG2E -2.8853900817779268f   // -2*log2(e)

__device__ __forceinline__ h16x8 loadB(const float* __restrict__ W, int ld, int ro,
                                       int k0, int kmax, float scale) {
    h16x8 r;
    #pragma unroll
    for (int i = 0; i < 8; ++i) {
        const int k = k0 + i;
        r[i] = (h16)((k < kmax) ? scale * W[(size_t)ro * ld + k] : 0.f);
    }
    return r;
}

struct Par0 { static constexpr int value = 0; };
struct Par1 { static constexpr int value = 1; };

__global__ __attribute__((amdgpu_flat_work_group_size(NTH, NTH), amdgpu_waves_per_eu(3)))
void lstm_mfma(
    const float* __restrict__ x,
    const float* __restrict__ wih0, const float* __restrict__ whh0,
    const float* __restrict__ bih0, const float* __restrict__ bhh0,
    const float* __restrict__ wih1, const float* __restrict__ whh1,
    const float* __restrict__ bih1, const float* __restrict__ bhh1,
    const float* __restrict__ wih2, const float* __restrict__ whh2,
    const float* __restrict__ bih2, const float* __restrict__ bhh2,
    const float* __restrict__ wfc, const float* __restrict__ bfc,
    float* __restrict__ out)
{
    const int tid  = threadIdx.x;
    const int w    = tid >> 6;
    const int wl   = w >> 2;          // layer 0..2
    const int wg   = w & 3;           // gate-tile group
    const int lane = tid & 63;
    const int nloc = lane & 15;
    const int kg   = lane >> 4;       // sample (C-row 4*kg, reg 0)
    const int b4   = blockIdx.x * 4;
    const int u    = wg * 16 + nloc;

    __shared__ alignas(16) h16 XL[2 * XCH];
    __shared__ alignas(16) h16 HR[3 * HLAY];

    // ---------------- B fragments (pre-scaled, R17) ----------------
    h16x8 Bf[4][4];
    float bias[4];
    #pragma unroll
    for (int g = 0; g < 4; ++g) {
        const int ro = g * 64 + u;
        const float sc = (g == 2) ? N2LOG2E : NLOG2E;
        if (wl == 0) {
            Bf[g][0] = loadB(wih0, 22, ro, kg * 8,      22, sc);
            Bf[g][1] = loadB(whh0, 64, ro, kg * 8,      64, sc);
            Bf[g][2] = loadB(whh0, 64, ro, 32 + kg * 8, 64, sc);
            Bf[g][3] = Bf[g][2];
            bias[g]  = sc * (bih0[ro] + bhh0[ro]);
        } else if (wl == 1) {
            Bf[g][0] = loadB(wih1, 64, ro, kg * 8,      64, sc);
            Bf[g][1] = loadB(wih1, 64, ro, 32 + kg * 8, 64, sc);
            Bf[g][2] = loadB(whh1, 64, ro, kg * 8,      64, sc);
            Bf[g][3] = loadB(whh1, 64, ro, 32 + kg * 8, 64, sc);
            bias[g]  = sc * (bih1[ro] + bhh1[ro]);
        } else {
            Bf[g][0] = loadB(wih2, 64, ro, kg * 8,      64, sc);
            Bf[g][1] = loadB(wih2, 64, ro, 32 + kg * 8, 64, sc);
            Bf[g][2] = loadB(whh2, 64, ro, kg * 8,      64, sc);
            Bf[g][3] = loadB(whh2, 64, ro, 32 + kg * 8, 64, sc);
            bias[g]  = sc * (bih2[ro] + bhh2[ro]);
        }
    }

    // ---------------- zero LDS ----------------
    {
        int* xz = (int*)XL;
        for (int i = tid; i < XCH; i += NTH) xz[i] = 0;
        int* hz = (int*)HR;
        for (int i = tid; i < (3 * HLAY) / 2; i += NTH) hz[i] = 0;
    }
    __syncthreads();

    // ---------------- x staging ----------------
    auto stage_x = [&](int chunk) {
        if (tid < 4 * 22) {
            const int bl = tid / 22, ii = tid - bl * 22;
            const float* src = x + (size_t)(b4 + bl) * (22 * 512) + (size_t)ii * 512
                                 + chunk * 32;
            h16* dst = &XL[(chunk & 1) * XCH + (ii >> 3) * 128 + (4 * bl) * 8 + (ii & 7)];
            #pragma unroll
            for (int q = 0; q < 8; ++q) {
                const float4 v = ((const float4*)src)[q];
                dst[(q * 4 + 0) * XSLB] = (h16)v.x;
                dst[(q * 4 + 1) * XSLB] = (h16)v.y;
                dst[(q * 4 + 2) * XSLB] = (h16)v.z;
                dst[(q * 4 + 3) * XSLB] = (h16)v.w;
            }
        }
    };
    stage_x(0);

    // ---------------- per-lane hoisted constants ----------------
    const int lo8  = lane * 8;
    const int hoff = (u >> 3) * 128 + kg * 32 + (u & 7);
    const int bj   = lane & 3;
    const int boff = (lane >> 4) * 128 + ((lane & 15) >> 2) * 32;
    const int bjH  = bj * HSLB + boff;    // batch h per-lane offset (hoisted)
    const int bjX  = bj * XSLB + boff;    // batch x per-lane offset (hoisted)

    float cst = 0.f;

    // R17 ew: 7 trans (5 exp2 + 2 rcp), fused denominators
    auto ew = [&](const f32x4& zi, const f32x4& zf, const f32x4& zg, const f32x4& zo,
                  h16* hb) {
        const float ei = __builtin_amdgcn_exp2f(zi[0]);
        const float ef = __builtin_amdgcn_exp2f(zf[0]);
        const float eg = __builtin_amdgcn_exp2f(zg[0]);
        const float eo = __builtin_amdgcn_exp2f(zo[0]);
        const float pig = (1.f + ei) * (1.f + eg);
        const float pf  = 1.f + ef;
        const float n   = cst * pig + (1.f - eg) * pf;
        const float c   = n * __builtin_amdgcn_rcpf(pf * pig);
        cst = c;
        const float ea  = fminf(c * N2LOG2E, 126.f);
        const float ec  = __builtin_amdgcn_exp2f(ea);
        const float h   = (1.f - ec)
                        * __builtin_amdgcn_rcpf((1.f + ec) * (1.f + eo));
        hb[hoff] = (h16)h;
    };

    // persistent broadcast-bias C tuples (hoisted out of the loop)
    f32x4 zb4[4];
    #pragma unroll
    for (int g = 0; g < 4; ++g)
        zb4[g] = f32x4{bias[g], bias[g], bias[g], bias[g]};

    __syncthreads();

    h16* const HR0 = HR;
    h16* const HR1 = HR + HLAY;
    h16* const HR2 = HR + 2 * HLAY;

    // ============== EDGE group (runtime slots; groups 0,1,128,129) ==============
    auto egroup = [&](int G) {
        f32x4 zB[4];
        if (wl == 0) {
            const bool act = (G <= 127);
            if (act) {
                const int t0 = 4 * G;
                const h16x8 axB = *(const h16x8*)
                    &XL[((t0 >> 5) & 1) * XCH + (t0 & 31) * XSLB + bjX];
                #pragma unroll
                for (int g = 0; g < 4; ++g) zB[g] = MFMA16(axB, Bf[g][0], zb4[g]);
            }
            #pragma unroll
            for (int j = 0; j < 4; ++j) {
                if (act) {
                    const int t = 4 * G + j;
                    const h16* sr = HR0 + ((t - 1) & 7) * HSLB;
                    h16*       sw = HR0 + (t & 7) * HSLB;
                    const h16x8 alo = *(const h16x8*)(sr + lo8);
                    const h16x8 ahi = *(const h16x8*)(sr + lo8 + 512);
                    f32x4 z[4];
                    #pragma unroll
                    for (int g = 0; g < 4; ++g) {
                        const f32x4 cin = {zB[g][j], 0.f, 0.f, 0.f};
                        z[g] = MFMA16(alo, Bf[g][1], cin);
                        z[g] = MFMA16(ahi, Bf[g][2], z[g]);
                    }
                    if (j == 0 && (G & 7) == 4 && (G >> 3) < 15) stage_x((G >> 3) + 1);
                    ew(z[0], z[1], z[2], z[3], sw);
                }
                __syncthreads();
            }
        } else if (wl == 1) {
            const bool act = (G >= 1 && G <= 128);
            if (act) {
                const int sB = 4 * G - 4;
                const h16* hb = HR0 + ((sB & 7) * HSLB) + bjH;   // no wrap in quad
                const h16x8 blo = *(const h16x8*)hb;
                const h16x8 bhi = *(const h16x8*)(hb + 512);
                #pragma unroll
                for (int g = 0; g < 4; ++g) {
                    f32x4 zt = MFMA16(blo, Bf[g][0], zb4[g]);
                    zB[g] = MFMA16(bhi, Bf[g][1], zt);
                }
            }
            #pragma unroll
            for (int j = 0; j < 4; ++j) {
                if (act) {
                    const int s = 4 * G - 4 + j;
                    const h16* sr = HR1 + ((s - 1) & 7) * HSLB;
                    h16*       sw = HR1 + (s & 7) * HSLB;
                    const h16x8 alo = *(const h16x8*)(sr + lo8);
                    const h16x8 ahi = *(const h16x8*)(sr + lo8 + 512);
                    f32x4 z[4];
                    #pragma unroll
                    for (int g = 0; g < 4; ++g) {
                        const f32x4 cin = {zB[g][j], 0.f, 0.f, 0.f};
                        z[g] = MFMA16(alo, Bf[g][2], cin);
                        z[g] = MFMA16(ahi, Bf[g][3], z[g]);
                    }
                    ew(z[0], z[1], z[2], z[3], sw);
                }
                __syncthreads();
            }
        } else {
            const bool act = (G >= 2);
            if (act) {
                const int sB = 4 * G - 8;
                const h16* hb = HR1 + ((sB & 7) * HSLB) + bjH;
                const h16x8 blo = *(const h16x8*)hb;
                const h16x8 bhi = *(const h16x8*)(hb + 512);
                #pragma unroll
                for (int g = 0; g < 4; ++g) {
                    f32x4 zt = MFMA16(blo, Bf[g][0], zb4[g]);
                    zB[g] = MFMA16(bhi, Bf[g][1], zt);
                }
            }
            #pragma unroll
            for (int j = 0; j < 4; ++j) {
                if (act) {
                    const int s = 4 * G - 8 + j;
                    const h16* sr = HR2 + ((s - 1) & 7) * HSLB;
                    h16*       sw = HR2 + (s & 7) * HSLB;
                    const h16x8 alo = *(const h16x8*)(sr + lo8);
                    const h16x8 ahi = *(const h16x8*)(sr + lo8 + 512);
                    f32x4 z[4];
                    #pragma unroll
                    for (int g = 0; g < 4; ++g) {
                        const f32x4 cin = {zB[g][j], 0.f, 0.f, 0.f};
                        z[g] = MFMA16(alo, Bf[g][2], cin);
                        z[g] = MFMA16(ahi, Bf[g][3], z[g]);
                    }
                    ew(z[0], z[1], z[2], z[3], sw);
                }
                __syncthreads();
            }
        }
    };

    // ======== STEADY group: PAR = G&1 -> ALL ring slots compile-time ========
    // L0 self:  sw=(4P+j)&7,  sr=(4P+j+7)&7 ;  batch: x (runtime slab base)
    // L1 self:  sw=(4P+j+4)&7, sr=(4P+j+3)&7 ; batch base = (P?0:4)*HSLB
    // L2 self:  sw=(4P+j)&7,  sr=(4P+j+7)&7 ;  batch base = (P?4:0)*HSLB
    auto sgroup = [&](int G, auto parc) {
        constexpr int P = decltype(parc)::value;
        f32x4 zB[4];
        if (wl == 0) {
            const h16* bx = &XL[((G >> 3) & 1) * XCH + 4 * (G & 7) * XSLB];
            const h16x8 axB = *(const h16x8*)(bx + bjX);
            #pragma unroll
            for (int g = 0; g < 4; ++g) zB[g] = MFMA16(axB, Bf[g][0], zb4[g]);
            #pragma unroll
            for (int j = 0; j < 4; ++j) {
                const h16* sr = HR0 + ((4 * P + j + 7) & 7) * HSLB;
                h16*       sw = HR0 + ((4 * P + j) & 7) * HSLB;
                const h16x8 alo = *(const h16x8*)(sr + lo8);
                const h16x8 ahi = *(const h16x8*)(sr + lo8 + 512);
                f32x4 z[4];
                #pragma unroll
                for (int g = 0; g < 4; ++g) {
                    const f32x4 cin = {zB[g][j], 0.f, 0.f, 0.f};
                    z[g] = MFMA16(alo, Bf[g][1], cin);
                    z[g] = MFMA16(ahi, Bf[g][2], z[g]);
                }
                if (j == 0 && (G & 7) == 4 && (G >> 3) < 15) stage_x((G >> 3) + 1);
                ew(z[0], z[1], z[2], z[3], sw);
                __syncthreads();
            }
        } else if (wl == 1) {
            const h16* hb = HR0 + (P ? 0 : 4) * HSLB + bjH;
            const h16x8 blo = *(const h16x8*)hb;
            const h16x8 bhi = *(const h16x8*)(hb + 512);
            #pragma unroll
            for (int g = 0; g < 4; ++g) {
                f32x4 zt = MFMA16(blo, Bf[g][0], zb4[g]);
                zB[g] = MFMA16(bhi, Bf[g][1], zt);
            }
            #pragma unroll
            for (int j = 0; j < 4; ++j) {
                const h16* sr = HR1 + ((4 * P + j + 3) & 7) * HSLB;
                h16*       sw = HR1 + ((4 * P + j + 4) & 7) * HSLB;
                const h16x8 alo = *(const h16x8*)(sr + lo8);
                const h16x8 ahi = *(const h16x8*)(sr + lo8 + 512);
                f32x4 z[4];
                #pragma unroll
                for (int g = 0; g < 4; ++g) {
                    const f32x4 cin = {zB[g][j], 0.f, 0.f, 0.f};
                    z[g] = MFMA16(alo, Bf[g][2], cin);
                    z[g] = MFMA16(ahi, Bf[g][3], z[g]);
                }
                ew(z[0], z[1], z[2], z[3], sw);
                __syncthreads();
            }
        } else {
            const h16* hb = HR1 + (P ? 4 : 0) * HSLB + bjH;
            const h16x8 blo = *(const h16x8*)hb;
            const h16x8 bhi = *(const h16x8*)(hb + 512);
            #pragma unroll
            for (int g = 0; g < 4; ++g) {
                f32x4 zt = MFMA16(blo, Bf[g][0], zb4[g]);
                zB[g] = MFMA16(bhi, Bf[g][1], zt);
            }
            #pragma unroll
            for (int j = 0; j < 4; ++j) {
                const h16* sr = HR2 + ((4 * P + j + 7) & 7) * HSLB;
                h16*       sw = HR2 + ((4 * P + j) & 7) * HSLB;
                const h16x8 alo = *(const h16x8*)(sr + lo8);
                const h16x8 ahi = *(const h16x8*)(sr + lo8 + 512);
                f32x4 z[4];
                #pragma unroll
                for (int g = 0; g < 4; ++g) {
                    const f32x4 cin = {zB[g][j], 0.f, 0.f, 0.f};
                    z[g] = MFMA16(alo, Bf[g][2], cin);
                    z[g] = MFMA16(ahi, Bf[g][3], z[g]);
                }
                ew(z[0], z[1], z[2], z[3], sw);
                __syncthreads();
            }
        }
    };

    egroup(0);
    egroup(1);
    #pragma unroll 1
    for (int GP = 1; GP <= 63; ++GP) {      // G = 2..127, slots compile-time
        sgroup(2 * GP, Par0{});
        sgroup(2 * GP + 1, Par1{});
    }
    egroup(128);
    egroup(129);

    // ------------- FC epilogue: h2(step 511) in ring slot 511&7 = 7 -----------
    if (tid < 16) {
        const int ms = tid >> 2, o = tid & 3;
        const h16* h2 = HR + 2 * HLAY + 7 * HSLB;
        float acc = bfc[o];
        #pragma unroll 1
        for (int uu = 0; uu < 64; ++uu)
            acc += (float)h2[(uu >> 3) * 128 + (4 * ms) * 8 + (uu & 7)] * wfc[o * 64 + uu];
        out[(b4 + ms) * 4 + o] = acc;
    }
}

extern "C" void kernel_launch(void* const* d_in, const int* in_sizes, int n_in,
                              void* d_out, int out_size, void* d_ws, size_t ws_size,
                              hipStream_t stream) {
    const float* x    = (const float*)d_in[0];
    const float* wih0 = (const float*)d_in[1];
    const float* whh0 = (const float*)d_in[2];
    const float* bih0 = (const float*)d_in[3];
    const float* bhh0 = (const float*)d_in[4];
    const float* wih1 = (const float*)d_in[5];
    const float* whh1 = (const float*)d_in[6];
    const float* bih1 = (const float*)d_in[7];
    const float* bhh1 = (const float*)d_in[8];
    const float* wih2 = (const float*)d_in[9];
    const float* whh2 = (const float*)d_in[10];
    const float* bih2 = (const float*)d_in[11];
    const float* bhh2 = (const float*)d_in[12];
    const float* wfc  = (const float*)d_in[13];
    const float* bfc  = (const float*)d_in[14];
    float* out = (float*)d_out;

    lstm_mfma<<<dim3(NBLK), dim3(NTH), 0, stream>>>(
        x, wih0, whh0, bih0, bhh0, wih1, whh1, bih1, bhh1,
        wih2, whh2, bih2, bhh2, wfc, bfc, out);
}